// Round 1
// 2264.242 us; speedup vs baseline: 1.0414x; 1.0414x over previous
//
#include <hip/hip_runtime.h>
#include <hip/hip_bf16.h>
#include <math.h>

#define Bq 2
#define Sq 1024
#define Dq 1024
#define Hq 16
#define DHq 64
#define FFq 4096
#define Eq 4
#define Kq 64
#define Mq 256
#define GATEq 128
#define BSq (Bq*Sq)
#define DEPTHF 1.25f
#define SCALEF 0.125f
#define DD (Dq*Dq)

typedef __hip_bfloat16 bf16;
typedef __attribute__((ext_vector_type(8))) __bf16 bf16x8;
typedef __attribute__((ext_vector_type(4))) float f32x4;

__device__ __forceinline__ float toF(float v){ return v; }
__device__ __forceinline__ float toF(bf16 v){ return __bfloat162float(v); }
__device__ __forceinline__ void stF(float* p, size_t i, float v){ p[i] = v; }
__device__ __forceinline__ void stF(bf16* p, size_t i, float v){ p[i] = __float2bfloat16(v); }
__device__ __forceinline__ float gelu_f(float x){
  const float c = 0.7978845608028654f;
  return 0.5f*x*(1.0f + tanhf(c*(x + 0.044715f*x*x*x)));
}
__device__ __forceinline__ unsigned short bfb(float f){
  bf16 h = __float2bfloat16(f);
  return *(unsigned short*)&h;
}
// inverse of the monotone uint map (uu = s<0 ? ~bits : bits|0x80000000)
__device__ __forceinline__ float thr_decode(unsigned c){
  unsigned ub = (c & 0x80000000u) ? (c & 0x7FFFFFFFu) : ~c;
  return __uint_as_float(ub);
}
// async global->LDS, 16B per lane; lds pointer must be wave-uniform (chunk base)
__device__ __forceinline__ void async_lds16(const void* g, void* lds) {
  __builtin_amdgcn_global_load_lds(
      (const __attribute__((address_space(1))) void*)(unsigned long long)(uintptr_t)g,
      (__attribute__((address_space(3))) void*)(unsigned)(uintptr_t)lds, 16, 0, 0);
}

// ---------------- dtype detector ----------------
__global__ __launch_bounds__(256)
void detect_kernel(const unsigned* __restrict__ xw, int* __restrict__ flag)
{
  __shared__ int cnt;
  if (threadIdx.x == 0) cnt = 0;
  __syncthreads();
  int c = 0;
  for (int i = threadIdx.x; i < 4096; i += 256) {
    unsigned e = (xw[i] >> 7) & 0xFFu;
    c += (e >= 0x70u && e <= 0x8Fu) ? 1 : 0;
  }
#pragma unroll
  for (int o = 32; o >= 1; o >>= 1) c += __shfl_xor(c, o);
  if ((threadIdx.x & 63) == 0) atomicAdd(&cnt, c);
  __syncthreads();
  if (threadIdx.x == 0) *flag = (cnt > 2048) ? 1 : 0;
}

// ---------------- convert x -> bf16 ----------------
__global__ __launch_bounds__(256)
void conv_x_kernel(const int* __restrict__ flag, const void* __restrict__ x, bf16* __restrict__ xb)
{
  int f = *flag;
  int i0 = (blockIdx.x*256 + threadIdx.x)*4;
  if (i0 >= BSq*Dq) return;
  if (f) {
    const bf16* s = (const bf16*)x;
#pragma unroll
    for (int k=0;k<4;k++) xb[i0+k] = s[i0+k];
  } else {
    const float* s = (const float*)x;
#pragma unroll
    for (int k=0;k<4;k++) xb[i0+k] = __float2bfloat16(s[i0+k]);
  }
}

// ---------------- pack all biases into bf16 arena ----------------
template<typename IT>
__device__ void packseg(bf16* dst, const IT* src, int len)
{
  for (int i = threadIdx.x; i < len; i += 256) dst[i] = __float2bfloat16(toF(src[i]));
}
__global__ __launch_bounds__(256)
void pack_bias_kernel(const int* __restrict__ flag, bf16* arena,
    const void* bq, const void* bk, const void* bv, const void* bo,
    const void* sq, const void* sk, const void* sv, const void* so,
    const void* pq, const void* pk, const void* pv, const void* po,
    const void* f1, const void* f2)
{
  int f = *flag;
  if (f) {
    packseg(arena+0,     (const bf16*)bq, 4096); packseg(arena+4096,  (const bf16*)bk, 4096);
    packseg(arena+8192,  (const bf16*)bv, 4096); packseg(arena+12288, (const bf16*)bo, 4096);
    packseg(arena+16384, (const bf16*)sq, 1024); packseg(arena+17408, (const bf16*)sk, 1024);
    packseg(arena+18432, (const bf16*)sv, 1024); packseg(arena+19456, (const bf16*)so, 1024);
    packseg(arena+20480, (const bf16*)pq, 1024); packseg(arena+21504, (const bf16*)pk, 1024);
    packseg(arena+22528, (const bf16*)pv, 1024); packseg(arena+23552, (const bf16*)po, 1024);
    packseg(arena+24576, (const bf16*)f1, 4096); packseg(arena+28672, (const bf16*)f2, 1024);
  } else {
    packseg(arena+0,     (const float*)bq, 4096); packseg(arena+4096,  (const float*)bk, 4096);
    packseg(arena+8192,  (const float*)bv, 4096); packseg(arena+12288, (const float*)bo, 4096);
    packseg(arena+16384, (const float*)sq, 1024); packseg(arena+17408, (const float*)sk, 1024);
    packseg(arena+18432, (const float*)sv, 1024); packseg(arena+19456, (const float*)so, 1024);
    packseg(arena+20480, (const float*)pq, 1024); packseg(arena+21504, (const float*)pk, 1024);
    packseg(arena+22528, (const float*)pv, 1024); packseg(arena+23552, (const float*)po, 1024);
    packseg(arena+24576, (const float*)f1, 4096); packseg(arena+28672, (const float*)f2, 1024);
  }
}

// ---------------- MFMA GEMM: C(2048xN) = act(A(2048xK) @ W(KxN) + bias) * rowscale [+C] ----------------
template<typename WT>
__device__ void gemm_core(bf16* As, unsigned* Bs,
    const bf16* __restrict__ A, const WT* __restrict__ W,
    const bf16* __restrict__ barena, int biasOff,
    const float* __restrict__ rowscale, bf16* __restrict__ C,
    int N, int K, int accum, int act)
{
  int tid = threadIdx.x;
  int lane = tid & 63, wave = tid >> 6;
  int wr = wave >> 1, wc = wave & 1;
  int bm = blockIdx.x * 128, bn = blockIdx.y * 128;

  int arow1 = wave*16 + (lane>>2);
  int akey = (arow1 >> 1) & 3;
  int acol = ((lane & 3) ^ akey) * 8;
  const bf16* aP1 = A + (size_t)(bm + arow1)*K + acol;
  const bf16* aP2 = A + (size_t)(bm + arow1 + 64)*K + acol;
  bf16* ldsA1 = As + wave*512;
  bf16* ldsA2 = As + (wave+4)*512;

  int kp = tid >> 4, nb8 = (tid & 15)*8;
  const WT* wP = W + (size_t)(2*kp)*N + bn + nb8;
  unsigned* bDst = Bs + kp*132 + nb8;

  f32x4 acc[4][4];
#pragma unroll
  for (int i=0;i<4;i++)
#pragma unroll
    for (int j=0;j<4;j++) acc[i][j] = (f32x4){0.f,0.f,0.f,0.f};

  int m = lane & 15, q = lane >> 4;
  int akey2 = (m >> 1) & 3;
  int aq = (q ^ akey2) * 8;

  for (int k0 = 0; k0 < K; k0 += 32) {
    __syncthreads();
    async_lds16(aP1, ldsA1);
    async_lds16(aP2, ldsA2);
    aP1 += 32; aP2 += 32;
    unsigned p[8];
    if constexpr (sizeof(WT) == 2) {
      const unsigned* s0 = (const unsigned*)wP;
      const unsigned* s1 = (const unsigned*)(wP + N);
      uint4 r0 = *(const uint4*)s0;
      uint4 r1 = *(const uint4*)s1;
      p[0] = (r0.x & 0xFFFFu) | (r1.x << 16);  p[1] = (r0.x >> 16) | (r1.x & 0xFFFF0000u);
      p[2] = (r0.y & 0xFFFFu) | (r1.y << 16);  p[3] = (r0.y >> 16) | (r1.y & 0xFFFF0000u);
      p[4] = (r0.z & 0xFFFFu) | (r1.z << 16);  p[5] = (r0.z >> 16) | (r1.z & 0xFFFF0000u);
      p[6] = (r0.w & 0xFFFFu) | (r1.w << 16);  p[7] = (r0.w >> 16) | (r1.w & 0xFFFF0000u);
    } else {
      const float* s0 = (const float*)wP;
      const float* s1 = (const float*)(wP + N);
#pragma unroll
      for (int e=0;e<8;e++)
        p[e] = (unsigned)bfb(s0[e]) | ((unsigned)bfb(s1[e]) << 16);
    }
    wP += (size_t)32*N;
    *(uint4*)(bDst)     = make_uint4(p[0],p[1],p[2],p[3]);
    *(uint4*)(bDst + 4) = make_uint4(p[4],p[5],p[6],p[7]);
    asm volatile("s_waitcnt vmcnt(0)" ::: "memory");
    __syncthreads();

    bf16x8 av[4], bv[4];
#pragma unroll
    for (int i=0;i<4;i++)
      av[i] = *(const bf16x8*)&As[(wr*64 + i*16 + m)*32 + aq];
#pragma unroll
    for (int j=0;j<4;j++) {
      int n = wc*64 + j*16 + m;
      unsigned b0 = Bs[(q*4+0)*132 + n];
      unsigned b1 = Bs[(q*4+1)*132 + n];
      unsigned b2 = Bs[(q*4+2)*132 + n];
      unsigned b3 = Bs[(q*4+3)*132 + n];
      uint4 bb = make_uint4(b0,b1,b2,b3);
      bv[j] = *(const bf16x8*)&bb;
    }
#pragma unroll
    for (int i=0;i<4;i++)
#pragma unroll
      for (int j=0;j<4;j++)
        acc[i][j] = __builtin_amdgcn_mfma_f32_16x16x32_bf16(av[i], bv[j], acc[i][j], 0, 0, 0);
  }

#pragma unroll
  for (int i=0;i<4;i++) {
    int row0 = bm + wr*64 + i*16 + q*4;
#pragma unroll
    for (int j=0;j<4;j++) {
      int col = bn + wc*64 + j*16 + m;
      float bvv = barena ? toF(barena[biasOff + col]) : 0.f;
#pragma unroll
      for (int r=0;r<4;r++) {
        float v = acc[i][j][r] + bvv;
        if (act) v = gelu_f(v);
        if (rowscale) v *= rowscale[row0 + r];
        size_t idx = (size_t)(row0 + r)*N + col;
        if (accum) v += toF(C[idx]);
        C[idx] = __float2bfloat16(v);
      }
    }
  }
}

__global__ __launch_bounds__(256)
void gemm_k(const int* __restrict__ flag, const bf16* A,
            const void* W0, const void* W1, const void* W2, long eOff,
            const bf16* barena, int biasOff, int biasZStride,
            const float* rowscale, bf16* Cbase, long czStride,
            int N, int K, int accum, int act)
{
  __shared__ bf16 As[128*32];
  __shared__ unsigned Bs[16*132];
  int z = blockIdx.z;
  const void* Wp = (z==0) ? W0 : (z==1) ? W1 : W2;
  bf16* C = Cbase + (size_t)z * czStride;
  int bOff = biasOff + z*biasZStride;
  if (*flag) gemm_core<bf16>(As, Bs, A, (const bf16*)Wp + eOff, barena, bOff, rowscale, C, N, K, accum, act);
  else       gemm_core<float>(As, Bs, A, (const float*)Wp + eOff, barena, bOff, rowscale, C, N, K, accum, act);
}

// ---------------- V transpose: V(b,s,h,d) -> Vt(b,h,d,s) ----------------
__global__ __launch_bounds__(256)
void vtrans_kernel(const bf16* __restrict__ V, bf16* __restrict__ Vt)
{
  __shared__ bf16 t[64][72];     // 72 = 64 + 8 pad; rows 144 B (16B aligned)
  int bh = blockIdx.x;           // b*16 + h
  int sc_ = blockIdx.y;          // S/64 chunks
  int b = bh >> 4, h = bh & 15;
  int tid = threadIdx.x;
  {
    int s = tid >> 2, dd = (tid & 3) * 16;
    const bf16* src = &V[((size_t)b*Sq + sc_*64 + s)*Dq + h*64 + dd];
    uint4 a0 = *(const uint4*)src;
    uint4 a1 = *(const uint4*)(src + 8);
    *(uint4*)&t[s][dd]     = a0;
    *(uint4*)&t[s][dd + 8] = a1;
  }
  __syncthreads();
  {
    int d = tid >> 2, sp = (tid & 3) * 16;
    unsigned short buf[16];
#pragma unroll
    for (int e = 0; e < 16; e++) {
      bf16 v = t[sp + e][d];
      buf[e] = *(unsigned short*)&v;
    }
    bf16* dst = &Vt[((size_t)bh*DHq + d)*Sq + sc_*64 + sp];
    *(uint4*)dst       = *(uint4*)&buf[0];
    *(uint4*)(dst + 8) = *(uint4*)&buf[8];
  }
}

// ---------------- MFMA fused attention (dense / exact top-K sparse) ----------------
// One block = 16 query rows of one (b,h). O may alias Q.
// R1 change: sparse bit-descend compares in FLOAT domain against the decoded
// candidate threshold (no uu[64] array -> no VGPR spill to scratch), plus
// block-uniform early exit once every row's accepted count == K (exact: a
// K-sized superset of the reference mask must equal it).
template<int SPARSE>
__global__ __launch_bounds__(256, 4)
void attn_kernel(const bf16* __restrict__ Q, const bf16* __restrict__ K,
                 const bf16* __restrict__ Vt, bf16* __restrict__ O)
{
  const int PAST = 1032;                    // pa stride (bf16), row = 2064 B (16B-aligned)
  __shared__ bf16 pa[16*PAST];              // 33 KB: p in A-operand layout
  __shared__ float partA[64], partB[64];
  __shared__ int cntb[2][64];

  int blk = blockIdx.x;
  int rb = blk & 63;
  int h  = (blk >> 6) & 15;
  int b  = blk >> 10;
  int tid = threadIdx.x, lane = tid & 63, wave = tid >> 6;
  int m = lane & 15, q = lane >> 4;
  size_t base = ((size_t)b*Sq)*Dq + (size_t)h*DHq;
  int q0 = rb*16;

  // Q A-frags (k=0..31, 32..63)
  const bf16* qrow = &Q[base + (size_t)(q0+m)*Dq + q*8];
  bf16x8 aq0 = *(const bf16x8*)qrow;
  bf16x8 aq1 = *(const bf16x8*)(qrow + 32);

  // ---- QK^T: wave covers score cols [wave*256, wave*256+256), scores in regs ----
  f32x4 cc[16];
#pragma unroll
  for (int t = 0; t < 16; t++) {
    int j0 = wave*256 + t*16;
    const bf16* kp = &K[base + (size_t)(j0+m)*Dq + q*8];
    bf16x8 b0 = *(const bf16x8*)kp;
    bf16x8 b1 = *(const bf16x8*)(kp + 32);
    f32x4 c = {0.f,0.f,0.f,0.f};
    c = __builtin_amdgcn_mfma_f32_16x16x32_bf16(aq0, b0, c, 0, 0, 0);
    c = __builtin_amdgcn_mfma_f32_16x16x32_bf16(aq1, b1, c, 0, 0, 0);
#pragma unroll
    for (int r=0;r<4;r++) c[r] *= SCALEF;
    cc[t] = c;
  }

  // ---- sparse: exact kth-largest per row via bit-descend on monotone uint map.
  // Counting is done with float compares against the decoded candidate
  // threshold, so only cc[] stays live (no spill). Early exit when every
  // row's last-accepted count is exactly K.
  unsigned lo[4] = {0u,0u,0u,0u};
  if (SPARSE) {
    int cnt_cur[4] = {Sq, Sq, Sq, Sq};
    for (int bit = 31; bit >= 0; bit--) {
      int par = bit & 1;
      unsigned cand[4];
      float candf[4];
      int c4[4] = {0,0,0,0};
#pragma unroll
      for (int r=0;r<4;r++) {
        cand[r] = lo[r] | (1u << bit);
        candf[r] = thr_decode(cand[r]);
      }
#pragma unroll
      for (int t=0;t<16;t++)
#pragma unroll
        for (int r=0;r<4;r++) c4[r] += (cc[t][r] >= candf[r]) ? 1 : 0;
#pragma unroll
      for (int o=1;o<16;o<<=1)
#pragma unroll
        for (int r=0;r<4;r++) c4[r] += __shfl_xor(c4[r], o);
      if (m == 0) {
#pragma unroll
        for (int r=0;r<4;r++) cntb[par][wave*16 + q*4 + r] = c4[r];
      }
      __syncthreads();
      int done = 1;
#pragma unroll
      for (int r=0;r<4;r++) {
        int row = q*4 + r;
        int tot = cntb[par][row] + cntb[par][16+row] + cntb[par][32+row] + cntb[par][48+row];
        if (tot >= Kq) { lo[r] = cand[r]; cnt_cur[r] = tot; }
        done &= (cnt_cur[r] == Kq) ? 1 : 0;
      }
      // AND across the 4 q-groups; identical in every wave -> block-uniform break
      done &= __shfl_xor(done, 16);
      done &= __shfl_xor(done, 32);
      if (done) break;
    }
  }

  // ---- row max (global max is always in top-K, so no mask needed) ----
  float mrow[4];
#pragma unroll
  for (int r=0;r<4;r++) {
    float v = -1e30f;
#pragma unroll
    for (int t=0;t<16;t++) v = fmaxf(v, cc[t][r]);
#pragma unroll
    for (int o=1;o<16;o<<=1) v = fmaxf(v, __shfl_xor(v, o));
    mrow[r] = v;
  }
  if (m == 0) {
#pragma unroll
    for (int r=0;r<4;r++) partA[wave*16 + q*4 + r] = mrow[r];
  }
  __syncthreads();
#pragma unroll
  for (int r=0;r<4;r++) {
    int row = q*4 + r;
    mrow[r] = fmaxf(fmaxf(partA[row], partA[16+row]), fmaxf(partA[32+row], partA[48+row]));
  }

  // ---- p = exp(s - m) (masked for sparse), write bf16 to pa, accumulate row sums ----
  float thrf[4];
  if (SPARSE) {
#pragma unroll
    for (int r=0;r<4;r++) {
      // guard: tiny-lo decodes into the NaN region; uint semantics there are
      // "include everything", which -INF reproduces
      thrf[r] = (!(lo[r] & 0x80000000u) && lo[r] <= 0x007FFFFFu)
                    ? -INFINITY : thr_decode(lo[r]);
    }
  }
  float rsum[4] = {0.f,0.f,0.f,0.f};
#pragma unroll
  for (int t=0;t<16;t++) {
    int col = wave*256 + t*16 + m;
#pragma unroll
    for (int r=0;r<4;r++) {
      float p;
      if (SPARSE) p = (cc[t][r] >= thrf[r]) ? __expf(cc[t][r] - mrow[r]) : 0.f;
      else        p = __expf(cc[t][r] - mrow[r]);
      rsum[r] += p;
      pa[(q*4+r)*PAST + col] = __float2bfloat16(p);
    }
  }
#pragma unroll
  for (int r=0;r<4;r++)
#pragma unroll
    for (int o=1;o<16;o<<=1) rsum[r] += __shfl_xor(rsum[r], o);
  if (m == 0) {
#pragma unroll
    for (int r=0;r<4;r++) partB[wave*16 + q*4 + r] = rsum[r];
  }
  __syncthreads();   // also makes pa visible for PV
#pragma unroll
  for (int r=0;r<4;r++) {
    int row = q*4 + r;
    rsum[r] = partB[row] + partB[16+row] + partB[32+row] + partB[48+row];
    rsum[r] = fmaxf(rsum[r], 1e-30f);
  }

  // ---- PV: wave covers dh cols [wave*16, wave*16+16); B-frags from transposed V ----
  const bf16* vtp = &Vt[((size_t)(b*Hq + h)*DHq + wave*16 + m)*Sq];
  f32x4 oc = {0.f,0.f,0.f,0.f};
#pragma unroll 8
  for (int ks = 0; ks < 32; ks++) {
    bf16x8 af = *(const bf16x8*)&pa[m*PAST + ks*32 + q*8];
    bf16x8 bv = *(const bf16x8*)&vtp[ks*32 + q*8];
    oc = __builtin_amdgcn_mfma_f32_16x16x32_bf16(af, bv, oc, 0, 0, 0);
  }
#pragma unroll
  for (int r=0;r<4;r++) {
    O[base + (size_t)(q0 + q*4 + r)*Dq + wave*16 + m] = __float2bfloat16(oc[r] / rsum[r]);
  }
}

// ---------------- performer pass 1: kv = pk^T v, z = sum pk ----------------
template<typename WT>
__device__ void perf_kv_body(bf16* wfs, float* krow, float* vrow, float* pkrow,
                             const bf16* __restrict__ Kb, const bf16* __restrict__ V,
                             const WT* __restrict__ wf, float* __restrict__ kv,
                             float* __restrict__ z)
{
  const int SLEN = Sq/8;
  int bh = blockIdx.x;
  int chunk = blockIdx.y;
  int h = bh & (Hq-1), b = bh >> 4;
  int tid = threadIdx.x;
  for (int l = tid; l < DHq*Mq; l += 256)
    wfs[l] = __float2bfloat16(toF(wf[l]));
  int d = tid & 63, g = tid >> 6;
  float kvacc[64];
#pragma unroll
  for (int i=0;i<64;i++) kvacc[i]=0.f;
  float zacc = 0.f;
  size_t base = ((size_t)b*Sq)*Dq + (size_t)h*DHq;
  for (int s = chunk*SLEN; s < (chunk+1)*SLEN; s++) {
    __syncthreads();
    if (tid < 64)       krow[tid]    = toF(Kb[base + (size_t)s*Dq + tid]);
    else if (tid < 128) vrow[tid-64] = toF(V [base + (size_t)s*Dq + (tid-64)]);
    __syncthreads();
    float a = 0.f;
#pragma unroll
    for (int dd = 0; dd < DHq; dd++) a += krow[dd]*toF(wfs[dd*Mq + tid]);
    float pk = fmaxf(a, 0.f);
    pkrow[tid] = pk;
    zacc += pk;
    __syncthreads();
    float vd = vrow[d];
#pragma unroll
    for (int i = 0; i < 64; i++) kvacc[i] += pkrow[g*64+i]*vd;
  }
  float* kvp = kv + (size_t)bh*Mq*DHq;
  for (int i = 0; i < 64; i++) atomicAdd(&kvp[(size_t)(g*64+i)*DHq + d], kvacc[i]);
  atomicAdd(&z[(size_t)bh*Mq + tid], zacc);
}

__global__ __launch_bounds__(256)
void perf_kv_kernel(const int* __restrict__ flag, const bf16* Kb, const bf16* V,
                    const void* wf, float* kv, float* z)
{
  __shared__ bf16 wfs[DHq*Mq];
  __shared__ float krow[DHq], vrow[DHq], pkrow[Mq];
  if (*flag) perf_kv_body<bf16>(wfs, krow, vrow, pkrow, Kb, V, (const bf16*)wf, kv, z);
  else       perf_kv_body<float>(wfs, krow, vrow, pkrow, Kb, V, (const float*)wf, kv, z);
}

// ---------------- performer pass 2 (O may alias Q) ----------------
template<typename WT>
__device__ void perf_out_body(bf16* wfs, float* qrow, float* pqrow, float* redn, float* redd,
                              const bf16* __restrict__ Q, const WT* __restrict__ wf,
                              const float* __restrict__ kv, const float* __restrict__ z,
                              bf16* __restrict__ O)
{
  const int TC = 64;
  int blk = blockIdx.x;
  int tc = blk & (Sq/TC - 1);
  int h = (blk / (Sq/TC)) & (Hq-1);
  int b = blk / ((Sq/TC)*Hq);
  int bh = b*Hq + h;
  int tid = threadIdx.x;
  for (int l = tid; l < DHq*Mq; l += 256)
    wfs[l] = __float2bfloat16(toF(wf[l]));
  int d = tid & 63, g = tid >> 6;
  size_t base = ((size_t)b*Sq)*Dq + (size_t)h*DHq;
  const float* kvp = kv + (size_t)bh*Mq*DHq;
  const float* zp  = z  + (size_t)bh*Mq;
  for (int s = tc*TC; s < (tc+1)*TC; s++) {
    __syncthreads();
    if (tid < 64) qrow[tid] = toF(Q[base + (size_t)s*Dq + tid]);
    __syncthreads();
    float a = 0.f;
#pragma unroll
    for (int dd = 0; dd < DHq; dd++) a += qrow[dd]*toF(wfs[dd*Mq + tid]);
    float pq = fmaxf(a, 0.f);
    pqrow[tid] = pq;
    float pd = pq * zp[tid];
#pragma unroll
    for (int o=32;o>=1;o>>=1) pd += __shfl_xor(pd, o);
    if ((tid & 63) == 0) redd[g] = pd;
    __syncthreads();
    float den = redd[0]+redd[1]+redd[2]+redd[3] + 1e-6f;
    float np = 0.f;
#pragma unroll
    for (int i = 0; i < 64; i++) np += pqrow[g*64+i]*kvp[(size_t)(g*64+i)*DHq + d];
    redn[g*DHq + d] = np;
    __syncthreads();
    if (g == 0) {
      float num = redn[0*DHq+d]+redn[1*DHq+d]+redn[2*DHq+d]+redn[3*DHq+d];
      stF(O, base + (size_t)s*Dq + d, num / den);
    }
  }
}

__global__ __launch_bounds__(256)
void perf_out_kernel(const int* __restrict__ flag, const bf16* Q, const void* wf,
                     const float* kv, const float* z, bf16* O)
{
  __shared__ bf16 wfs[DHq*Mq];
  __shared__ float qrow[DHq], pqrow[Mq];
  __shared__ float redn[4*DHq];
  __shared__ float redd[4];
  if (*flag) perf_out_body<bf16>(wfs, qrow, pqrow, redn, redd, Q, (const bf16*)wf, kv, z, O);
  else       perf_out_body<float>(wfs, qrow, pqrow, redn, redd, Q, (const float*)wf, kv, z, O);
}

// ---------------- LayerNorm ----------------
template<typename IT>
__device__ void ln_body(float* buf, float* red, const IT* __restrict__ xb,
                        const void* Ap, const void* Bp,
                        const IT* __restrict__ g, const IT* __restrict__ be,
                        void* out, int mode)
{
  int row = blockIdx.x;
  int tid = threadIdx.x;
  size_t off = (size_t)row*Dq;
  for (int dd = tid; dd < Dq; dd += 256) {
    float v;
    if (mode == 0)      v = toF(xb[off+dd]) + toF(((const bf16*)Ap)[off+dd]);
    else if (mode == 1) v = toF(((const bf16*)Ap)[off+dd]) + toF(((const bf16*)Bp)[off+dd]);
    else                v = toF(((const bf16*)Ap)[off+dd]);
    buf[dd] = v;
  }
  __syncthreads();
  float s = 0.f, q = 0.f;
  for (int dd = tid; dd < Dq; dd += 256) { float v = buf[dd]; s += v; q += v*v; }
#pragma unroll
  for (int o=32;o>=1;o>>=1) { s += __shfl_xor(s,o); q += __shfl_xor(q,o); }
  int w = tid >> 6;
  if ((tid & 63) == 0) { red[w] = s; red[4+w] = q; }
  __syncthreads();
  if (tid == 0) {
    float S1 = red[0]+red[1]+red[2]+red[3];
    float Q1 = red[4]+red[5]+red[6]+red[7];
    float mu = S1 / (float)Dq;
    float var = Q1 / (float)Dq - mu*mu;
    red[8] = mu; red[9] = rsqrtf(fmaxf(var, 0.f) + 1e-5f);
  }
  __syncthreads();
  float mu = red[8], inv = red[9];
  for (int dd = tid; dd < Dq; dd += 256) {
    float v = (buf[dd]-mu)*inv*toF(g[dd]) + toF(be[dd]);
    if (mode == 2) stF((IT*)out, off+dd, v);
    else           stF((bf16*)out, off+dd, v);
  }
}

__global__ __launch_bounds__(256)
void ln_kernel(const int* __restrict__ flag, const void* xb, const void* A, const void* Bv,
               const void* g, const void* be, void* out, int mode)
{
  __shared__ float buf[Dq];
  __shared__ float red[10];
  if (*flag) ln_body<bf16>(buf, red, (const bf16*)xb, A, Bv, (const bf16*)g, (const bf16*)be, out, mode);
  else       ln_body<float>(buf, red, (const float*)xb, A, Bv, (const float*)g, (const float*)be, out, mode);
}

// ---------------- avg over S ----------------
template<typename IT>
__device__ void avg_body(const IT* __restrict__ x, float* __restrict__ avg)
{
  int i = blockIdx.x*256 + threadIdx.x;
  if (i >= Bq*Dq) return;
  int b = i >> 10, dd = i & 1023;
  float s = 0.f;
  for (int ss = 0; ss < Sq; ss++) s += toF(x[((size_t)b*Sq+ss)*Dq + dd]);
  avg[i] = s * (1.0f/(float)Sq);
}
__global__ __launch_bounds__(256)
void avg_kernel(const int* __restrict__ flag, const void* x, float* avg)
{
  if (*flag) avg_body<bf16>((const bf16*)x, avg);
  else avg_body<float>((const float*)x, avg);
}

// ---------------- MoE router ----------------
template<typename IT>
__device__ void router_body(const IT* __restrict__ x, const IT* __restrict__ wr,
                            const IT* __restrict__ br, const float* __restrict__ cmb0,
                            float* __restrict__ gates_t)
{
  int row = blockIdx.x;
  int tid = threadIdx.x;
  size_t off = (size_t)row*Dq;
  float a0=0,a1=0,a2=0,a3=0;
  for (int dd = tid; dd < Dq; dd += 64) {
    float xv = toF(x[off+dd]);
    a0 += xv*toF(wr[dd*Eq+0]);
    a1 += xv*toF(wr[dd*Eq+1]);
    a2 += xv*toF(wr[dd*Eq+2]);
    a3 += xv*toF(wr[dd*Eq+3]);
  }
#pragma unroll
  for (int o=32;o>=1;o>>=1) {
    a0 += __shfl_xor(a0,o); a1 += __shfl_xor(a1,o);
    a2 += __shfl_xor(a2,o); a3 += __shfl_xor(a3,o);
  }
  if (tid == 0) {
    a0 += toF(br[0]); a1 += toF(br[1]); a2 += toF(br[2]); a3 += toF(br[3]);
    float m = fmaxf(fmaxf(a0,a1),fmaxf(a2,a3));
    float e0=__expf(a0-m), e1=__expf(a1-m), e2=__expf(a2-m), e3=__expf(a3-m);
    float inv = 1.f/(e0+e1+e2+e3);
    float sc = cmb0[row >> 10];
    gates_t[0*BSq+row]=e0*inv*sc; gates_t[1*BSq+row]=e1*inv*sc;
    gates_t[2*BSq+row]=e2*inv*sc; gates_t[3*BSq+row]=e3*inv*sc;
  }
}
__global__ __launch_bounds__(64)
void router_kernel(const int* __restrict__ flag, const void* x, const void* wr,
                   const void* br, const float* cmb0, float* gates_t)
{
  if (*flag) router_body<bf16>((const bf16*)x, (const bf16*)wr, (const bf16*)br, cmb0, gates_t);
  else       router_body<float>((const float*)x, (const float*)wr, (const float*)br, cmb0, gates_t);
}

// ---------------- tiny gate networks ----------------
template<typename IT>
__device__ void gates_body(float* g1, float* lg, float* ffnw, float* stg0, float* stg1, float* sffn,
    const float* __restrict__ avg,
    const IT* __restrict__ arg_w1, const IT* __restrict__ arg_b1,
    const IT* __restrict__ arg_w2, const IT* __restrict__ arg_b2,
    const IT* __restrict__ taa_wg, const IT* __restrict__ taa_bg,
    const IT* __restrict__ ag_w, const IT* __restrict__ ag_b,
    float* __restrict__ cmb0, float* __restrict__ rs_tg0,
    float* __restrict__ rs_tg1, float* __restrict__ rs_ffn)
{
  int tid = threadIdx.x;
  {
    int b = tid >> 7, j = tid & 127;
    float a = toF(arg_b1[j]);
    for (int dd = 0; dd < Dq; dd++) a += avg[b*Dq+dd]*toF(arg_w1[dd*GATEq+j]);
    g1[b*GATEq+j] = gelu_f(a);
  }
  __syncthreads();
  if (tid < 2) {
    float a = toF(arg_b2[1]);
    for (int j = 0; j < GATEq; j++) a += g1[tid*GATEq+j]*toF(arg_w2[j*2+1]);
    ffnw[tid] = 1.f/(1.f+__expf(-a));
  } else if (tid < 6) {
    int b = (tid-2)>>1, c = (tid-2)&1;
    float a = toF(taa_bg[c]);
    for (int dd = 0; dd < Dq; dd++) a += avg[b*Dq+dd]*toF(taa_wg[dd*2+c]);
    lg[b*2+c] = a;
  } else if (tid < 10) {
    int b = (tid-6)>>1, c = (tid-6)&1;
    float a = toF(ag_b[c]);
    for (int dd = 0; dd < Dq; dd++) a += avg[b*Dq+dd]*toF(ag_w[dd*2+c]);
    lg[4 + b*2+c] = a;
  }
  __syncthreads();
  if (tid < Bq) {
    int b = tid;
    float t0 = lg[b*2], t1 = lg[b*2+1];
    float m = fmaxf(t0,t1);
    float e0=__expf(t0-m), e1=__expf(t1-m), inv=1.f/(e0+e1);
    float tg0 = e0*inv, tg1 = e1*inv;
    float a0 = lg[4+b*2], a1l = lg[4+b*2+1];
    m = fmaxf(a0,a1l);
    float f0=__expf(a0-m), f1=__expf(a1l-m); inv = 1.f/(f0+f1);
    float ag0 = f0*inv, ag1 = f1*inv;
    cmb0[b] = ag0*DEPTHF;
    stg0[b] = tg0*ag1*DEPTHF;
    stg1[b] = tg1*ag1*DEPTHF;
    sffn[b] = ffnw[b]*DEPTHF;
  }
  __syncthreads();
  for (int i = tid; i < BSq; i += 256) {
    int b = i >> 10;
    rs_tg0[i] = stg0[b]; rs_tg1[i] = stg1[b]; rs_ffn[i] = sffn[b];
  }
}
__global__ __launch_bounds__(256)
void gates_small_kernel(const int* __restrict__ flag, const float* avg,
    const void* arg_w1, const void* arg_b1, const void* arg_w2, const void* arg_b2,
    const void* taa_wg, const void* taa_bg, const void* ag_w, const void* ag_b,
    float* cmb0, float* rs_tg0, float* rs_tg1, float* rs_ffn)
{
  __shared__ float g1[Bq*GATEq];
  __shared__ float lg[8];
  __shared__ float ffnw[2], stg0[2], stg1[2], sffn[2];
  if (*flag) gates_body<bf16>(g1, lg, ffnw, stg0, stg1, sffn, avg,
      (const bf16*)arg_w1,(const bf16*)arg_b1,(const bf16*)arg_w2,(const bf16*)arg_b2,
      (const bf16*)taa_wg,(const bf16*)taa_bg,(const bf16*)ag_w,(const bf16*)ag_b,
      cmb0, rs_tg0, rs_tg1, rs_ffn);
  else gates_body<float>(g1, lg, ffnw, stg0, stg1, sffn, avg,
      (const float*)arg_w1,(const float*)arg_b1,(const float*)arg_w2,(const float*)arg_b2,
      (const float*)taa_wg,(const float*)taa_bg,(const float*)ag_w,(const float*)ag_b,
      cmb0, rs_tg0, rs_tg1, rs_ffn);
}

extern "C" void kernel_launch(void* const* d_in, const int* in_sizes, int n_in,
                              void* d_out, int out_size, void* d_ws, size_t ws_size,
                              hipStream_t stream) {
  const void* x      = d_in[0];
  const void* arg_w1 = d_in[1];  const void* arg_b1 = d_in[2];
  const void* arg_w2 = d_in[3];  const void* arg_b2 = d_in[4];
  const void* moe_wr = d_in[5];  const void* moe_br = d_in[6];
  const void* moe_wq = d_in[7];  const void* moe_bq = d_in[8];
  const void* moe_wk = d_in[9];  const void* moe_bk = d_in[10];
  const void* moe_wv = d_in[11]; const void* moe_bv = d_in[12];
  const void* moe_wo = d_in[13]; const void* moe_bo = d_in[14];
  const void* sp_wq  = d_in[15]; const void* sp_bq  = d_in[16];
  const void* sp_wk  = d_in[17]; const void* sp_bk  = d_in[18];
  const void* sp_wv  = d_in[19]; const void* sp_bv  = d_in[20];
  const void* sp_wo  = d_in[21]; const void* sp_bo  = d_in[22];
  const void* pf_wq  = d_in[23]; const void* pf_bq  = d_in[24];
  const void* pf_wk  = d_in[25]; const void* pf_bk  = d_in[26];
  const void* pf_wv  = d_in[27]; const void* pf_bv  = d_in[28];
  const void* pf_wo  = d_in[29]; const void* pf_bo  = d_in[30];
  const void* pf_wf  = d_in[31];
  const void* taa_wg = d_in[32]; const void* taa_bg = d_in[33];
  const void* ag_w   = d_in[34]; const void* ag_b   = d_in[35];
  const void* ffn_w1 = d_in[36]; const void* ffn_b1 = d_in[37];
  const void* ffn_w2 = d_in[38]; const void* ffn_b2 = d_in[39];
  const void* n1_g   = d_in[40]; const void* n1_b   = d_in[41];
  const void* n2_g   = d_in[42]; const void* n2_b   = d_in[43];
  const void* n3_g   = d_in[44]; const void* n3_b   = d_in[45];

  char* w = (char*)d_ws;
  const size_t MB = 1024*1024;
  bf16* xb   = (bf16*)(w);            // [0,4)
  bf16* accb = (bf16*)(w + 4*MB);     // [4,8)
  bf16* Qb   = (bf16*)(w + 8*MB);     // [8,12)  (also attention O, in place)
  bf16* Kb   = (bf16*)(w + 12*MB);    // [12,16)
  bf16* Vb   = (bf16*)(w + 16*MB);    // [16,20)
  char* book = w + 20*MB;
  float* rs_tg0 = (float*)book;
  float* rs_tg1 = rs_tg0 + BSq;
  float* rs_ffn = rs_tg1 + BSq;
  float* cmb0   = rs_ffn + BSq;
  float* avgp   = cmb0 + 16;
  float* gates_t= avgp + Bq*Dq;
  float* zb     = gates_t + Eq*BSq;
  int*   dflag  = (int*)(zb + Bq*Hq*Mq);
  bf16*  barena = (bf16*)(dflag + 16);
  bf16*  Vt     = (bf16*)(w + 21*MB);  // [21,25) transposed V (b,h,d,s)
  float* kv     = (float*)(w + 21*MB); // [21,23) performer phase only (after attn)
  // FFN-phase aliases
  bf16* x1    = Vb;                    // [16,20)
  bf16* ffn_h = (bf16*)w;              // [0,16)
  bf16* tmpb  = (bf16*)(w + 21*MB);    // [21,25) over kv/Vt (dead)
  bf16* x2    = (bf16*)w;              // [0,4)

  detect_kernel<<<1, 256, 0, stream>>>((const unsigned*)x, dflag);
  hipMemsetAsync(zb, 0, (size_t)(Bq*Hq*Mq)*sizeof(float), stream);

  conv_x_kernel<<<BSq*Dq/1024, 256, 0, stream>>>(dflag, x, xb);
  pack_bias_kernel<<<1, 256, 0, stream>>>(dflag, barena,
      moe_bq, moe_bk, moe_bv, moe_bo, sp_bq, sp_bk, sp_bv, sp_bo,
      pf_bq, pf_bk, pf_bv, pf_bo, ffn_b1, ffn_b2);
  avg_kernel<<<(Bq*Dq+255)/256, 256, 0, stream>>>(dflag, x, avgp);
  gates_small_kernel<<<1, 256, 0, stream>>>(dflag, avgp, arg_w1, arg_b1, arg_w2, arg_b2,
      taa_wg, taa_bg, ag_w, ag_b, cmb0, rs_tg0, rs_tg1, rs_ffn);
  router_kernel<<<BSq, 64, 0, stream>>>(dflag, x, moe_wr, moe_br, cmb0, gates_t);

  dim3 gQKV(16, 8, 3);
  dim3 gOP(16, 8, 1);
  dim3 gF1(16, 32, 1);
  dim3 gVT(Bq*Hq, Sq/64);
  int nAttnBlk = Bq*Hq*(Sq/16);
  long czQKV = (long)BSq*Dq;

  // ---- MoE expert attentions ----
  for (int e = 0; e < Eq; e++) {
    long eOff = (long)e*DD;
    gemm_k<<<gQKV, 256, 0, stream>>>(dflag, xb, moe_wq, moe_wk, moe_wv, eOff,
        barena, e*1024, 4096, nullptr, Qb, czQKV, Dq, Dq, 0, 0);
    vtrans_kernel<<<gVT, 256, 0, stream>>>(Vb, Vt);
    attn_kernel<0><<<nAttnBlk, 256, 0, stream>>>(Qb, Kb, Vt, Qb);
    gemm_k<<<gOP, 256, 0, stream>>>(dflag, Qb, moe_wo, moe_wo, moe_wo, eOff,
        barena, 12288 + e*1024, 0, gates_t + (size_t)e*BSq, accb, 0, Dq, Dq, (e>0)?1:0, 0);
  }

  // ---- sparse attention ----
  gemm_k<<<gQKV, 256, 0, stream>>>(dflag, xb, sp_wq, sp_wk, sp_wv, 0,
      barena, 16384, 1024, nullptr, Qb, czQKV, Dq, Dq, 0, 0);
  vtrans_kernel<<<gVT, 256, 0, stream>>>(Vb, Vt);
  attn_kernel<1><<<nAttnBlk, 256, 0, stream>>>(Qb, Kb, Vt, Qb);
  gemm_k<<<gOP, 256, 0, stream>>>(dflag, Qb, sp_wo, sp_wo, sp_wo, 0,
      barena, 19456, 0, rs_tg0, accb, 0, Dq, Dq, 1, 0);

  // ---- performer attention (kv memset here: Vt region is dead now) ----
  gemm_k<<<gQKV, 256, 0, stream>>>(dflag, xb, pf_wq, pf_wk, pf_wv, 0,
      barena, 20480, 1024, nullptr, Qb, czQKV, Dq, Dq, 0, 0);
  hipMemsetAsync(kv, 0, (size_t)(Bq*Hq*Mq*DHq)*sizeof(float), stream);
  {
    dim3 gKV(Bq*Hq, 8);
    perf_kv_kernel<<<gKV, 256, 0, stream>>>(dflag, Kb, Vb, pf_wf, kv, zb);
  }
  perf_out_kernel<<<Bq*Hq*(Sq/64), 256, 0, stream>>>(dflag, Qb, pf_wf, kv, zb, Qb);
  gemm_k<<<gOP, 256, 0, stream>>>(dflag, Qb, pf_wo, pf_wo, pf_wo, 0,
      barena, 23552, 0, rs_tg1, accb, 0, Dq, Dq, 1, 0);

  // ---- LN1: x + accb -> x1 ----
  ln_kernel<<<BSq, 256, 0, stream>>>(dflag, x, accb, nullptr, n1_g, n1_b, x1, 0);

  // ---- FFN ----
  gemm_k<<<gF1, 256, 0, stream>>>(dflag, x1, ffn_w1, ffn_w1, ffn_w1, 0,
      barena, 24576, 0, nullptr, ffn_h, 0, FFq, Dq, 0, 1);
  gemm_k<<<gOP, 256, 0, stream>>>(dflag, ffn_h, ffn_w2, ffn_w2, ffn_w2, 0,
      barena, 28672, 0, rs_ffn, tmpb, 0, Dq, FFq, 0, 0);

  // ---- LN2, LN3 ----
  ln_kernel<<<BSq, 256, 0, stream>>>(dflag, nullptr, x1, tmpb, n2_g, n2_b, x2, 1);
  ln_kernel<<<BSq, 256, 0, stream>>>(dflag, nullptr, x2, nullptr, n3_g, n3_b, d_out, 2);
}

// Round 2
// 2014.356 us; speedup vs baseline: 1.1706x; 1.1241x over previous
//
#include <hip/hip_runtime.h>
#include <hip/hip_bf16.h>
#include <math.h>

#define Bq 2
#define Sq 1024
#define Dq 1024
#define Hq 16
#define DHq 64
#define FFq 4096
#define Eq 4
#define Kq 64
#define Mq 256
#define GATEq 128
#define BSq (Bq*Sq)
#define DEPTHF 1.25f
#define SCALEF 0.125f
#define DD (Dq*Dq)

typedef __hip_bfloat16 bf16;
typedef __attribute__((ext_vector_type(8))) __bf16 bf16x8;
typedef __attribute__((ext_vector_type(4))) float f32x4;

__device__ __forceinline__ float toF(float v){ return v; }
__device__ __forceinline__ float toF(bf16 v){ return __bfloat162float(v); }
__device__ __forceinline__ void stF(float* p, size_t i, float v){ p[i] = v; }
__device__ __forceinline__ void stF(bf16* p, size_t i, float v){ p[i] = __float2bfloat16(v); }
__device__ __forceinline__ float gelu_f(float x){
  const float c = 0.7978845608028654f;
  return 0.5f*x*(1.0f + tanhf(c*(x + 0.044715f*x*x*x)));
}
__device__ __forceinline__ unsigned short bfb(float f){
  bf16 h = __float2bfloat16(f);
  return *(unsigned short*)&h;
}
// inverse of the monotone uint map (uu = s<0 ? ~bits : bits|0x80000000)
__device__ __forceinline__ float thr_decode(unsigned c){
  unsigned ub = (c & 0x80000000u) ? (c & 0x7FFFFFFFu) : ~c;
  return __uint_as_float(ub);
}
// async global->LDS, 16B per lane; lds pointer must be wave-uniform (chunk base)
__device__ __forceinline__ void async_lds16(const void* g, void* lds) {
  __builtin_amdgcn_global_load_lds(
      (const __attribute__((address_space(1))) void*)(unsigned long long)(uintptr_t)g,
      (__attribute__((address_space(3))) void*)(unsigned)(uintptr_t)lds, 16, 0, 0);
}

// ---------------- dtype detector ----------------
__global__ __launch_bounds__(256)
void detect_kernel(const unsigned* __restrict__ xw, int* __restrict__ flag)
{
  __shared__ int cnt;
  if (threadIdx.x == 0) cnt = 0;
  __syncthreads();
  int c = 0;
  for (int i = threadIdx.x; i < 4096; i += 256) {
    unsigned e = (xw[i] >> 7) & 0xFFu;
    c += (e >= 0x70u && e <= 0x8Fu) ? 1 : 0;
  }
#pragma unroll
  for (int o = 32; o >= 1; o >>= 1) c += __shfl_xor(c, o);
  if ((threadIdx.x & 63) == 0) atomicAdd(&cnt, c);
  __syncthreads();
  if (threadIdx.x == 0) *flag = (cnt > 2048) ? 1 : 0;
}

// ---------------- convert x -> bf16 ----------------
__global__ __launch_bounds__(256)
void conv_x_kernel(const int* __restrict__ flag, const void* __restrict__ x, bf16* __restrict__ xb)
{
  int f = *flag;
  int i0 = (blockIdx.x*256 + threadIdx.x)*4;
  if (i0 >= BSq*Dq) return;
  if (f) {
    const bf16* s = (const bf16*)x;
#pragma unroll
    for (int k=0;k<4;k++) xb[i0+k] = s[i0+k];
  } else {
    const float* s = (const float*)x;
#pragma unroll
    for (int k=0;k<4;k++) xb[i0+k] = __float2bfloat16(s[i0+k]);
  }
}

// ---------------- pack all biases into bf16 arena ----------------
template<typename IT>
__device__ void packseg(bf16* dst, const IT* src, int len)
{
  for (int i = threadIdx.x; i < len; i += 256) dst[i] = __float2bfloat16(toF(src[i]));
}
__global__ __launch_bounds__(256)
void pack_bias_kernel(const int* __restrict__ flag, bf16* arena,
    const void* bq, const void* bk, const void* bv, const void* bo,
    const void* sq, const void* sk, const void* sv, const void* so,
    const void* pq, const void* pk, const void* pv, const void* po,
    const void* f1, const void* f2)
{
  int f = *flag;
  if (f) {
    packseg(arena+0,     (const bf16*)bq, 4096); packseg(arena+4096,  (const bf16*)bk, 4096);
    packseg(arena+8192,  (const bf16*)bv, 4096); packseg(arena+12288, (const bf16*)bo, 4096);
    packseg(arena+16384, (const bf16*)sq, 1024); packseg(arena+17408, (const bf16*)sk, 1024);
    packseg(arena+18432, (const bf16*)sv, 1024); packseg(arena+19456, (const bf16*)so, 1024);
    packseg(arena+20480, (const bf16*)pq, 1024); packseg(arena+21504, (const bf16*)pk, 1024);
    packseg(arena+22528, (const bf16*)pv, 1024); packseg(arena+23552, (const bf16*)po, 1024);
    packseg(arena+24576, (const bf16*)f1, 4096); packseg(arena+28672, (const bf16*)f2, 1024);
  } else {
    packseg(arena+0,     (const float*)bq, 4096); packseg(arena+4096,  (const float*)bk, 4096);
    packseg(arena+8192,  (const float*)bv, 4096); packseg(arena+12288, (const float*)bo, 4096);
    packseg(arena+16384, (const float*)sq, 1024); packseg(arena+17408, (const float*)sk, 1024);
    packseg(arena+18432, (const float*)sv, 1024); packseg(arena+19456, (const float*)so, 1024);
    packseg(arena+20480, (const float*)pq, 1024); packseg(arena+21504, (const float*)pk, 1024);
    packseg(arena+22528, (const float*)pv, 1024); packseg(arena+23552, (const float*)po, 1024);
    packseg(arena+24576, (const float*)f1, 4096); packseg(arena+28672, (const float*)f2, 1024);
  }
}

// ---------------- pack wf (DH x M) -> wfT (M x DH) bf16 ----------------
template<typename IT>
__device__ void packwft_body(const IT* __restrict__ wf, bf16* __restrict__ wft)
{
  int i = blockIdx.x*256 + threadIdx.x;     // 16384 total
  if (i >= DHq*Mq) return;
  int d = i >> 8, m = i & 255;              // wf[d][m]
  wft[m*DHq + d] = __float2bfloat16(toF(wf[(size_t)d*Mq + m]));
}
__global__ __launch_bounds__(256)
void pack_wft_kernel(const int* __restrict__ flag, const void* wf, bf16* wft)
{
  if (*flag) packwft_body<bf16>((const bf16*)wf, wft);
  else       packwft_body<float>((const float*)wf, wft);
}

// ---------------- MFMA GEMM: C(2048xN) = act(A(2048xK) @ W(KxN) + bias) * rowscale [+C] ----------------
template<typename WT>
__device__ void gemm_core(bf16* As, unsigned* Bs,
    const bf16* __restrict__ A, const WT* __restrict__ W,
    const bf16* __restrict__ barena, int biasOff,
    const float* __restrict__ rowscale, bf16* __restrict__ C,
    int N, int K, int accum, int act)
{
  int tid = threadIdx.x;
  int lane = tid & 63, wave = tid >> 6;
  int wr = wave >> 1, wc = wave & 1;
  int bm = blockIdx.x * 128, bn = blockIdx.y * 128;

  int arow1 = wave*16 + (lane>>2);
  int akey = (arow1 >> 1) & 3;
  int acol = ((lane & 3) ^ akey) * 8;
  const bf16* aP1 = A + (size_t)(bm + arow1)*K + acol;
  const bf16* aP2 = A + (size_t)(bm + arow1 + 64)*K + acol;
  bf16* ldsA1 = As + wave*512;
  bf16* ldsA2 = As + (wave+4)*512;

  int kp = tid >> 4, nb8 = (tid & 15)*8;
  const WT* wP = W + (size_t)(2*kp)*N + bn + nb8;
  unsigned* bDst = Bs + kp*132 + nb8;

  f32x4 acc[4][4];
#pragma unroll
  for (int i=0;i<4;i++)
#pragma unroll
    for (int j=0;j<4;j++) acc[i][j] = (f32x4){0.f,0.f,0.f,0.f};

  int m = lane & 15, q = lane >> 4;
  int akey2 = (m >> 1) & 3;
  int aq = (q ^ akey2) * 8;

  for (int k0 = 0; k0 < K; k0 += 32) {
    __syncthreads();
    async_lds16(aP1, ldsA1);
    async_lds16(aP2, ldsA2);
    aP1 += 32; aP2 += 32;
    unsigned p[8];
    if constexpr (sizeof(WT) == 2) {
      const unsigned* s0 = (const unsigned*)wP;
      const unsigned* s1 = (const unsigned*)(wP + N);
      uint4 r0 = *(const uint4*)s0;
      uint4 r1 = *(const uint4*)s1;
      p[0] = (r0.x & 0xFFFFu) | (r1.x << 16);  p[1] = (r0.x >> 16) | (r1.x & 0xFFFF0000u);
      p[2] = (r0.y & 0xFFFFu) | (r1.y << 16);  p[3] = (r0.y >> 16) | (r1.y & 0xFFFF0000u);
      p[4] = (r0.z & 0xFFFFu) | (r1.z << 16);  p[5] = (r0.z >> 16) | (r1.z & 0xFFFF0000u);
      p[6] = (r0.w & 0xFFFFu) | (r1.w << 16);  p[7] = (r0.w >> 16) | (r1.w & 0xFFFF0000u);
    } else {
      const float* s0 = (const float*)wP;
      const float* s1 = (const float*)(wP + N);
#pragma unroll
      for (int e=0;e<8;e++)
        p[e] = (unsigned)bfb(s0[e]) | ((unsigned)bfb(s1[e]) << 16);
    }
    wP += (size_t)32*N;
    *(uint4*)(bDst)     = make_uint4(p[0],p[1],p[2],p[3]);
    *(uint4*)(bDst + 4) = make_uint4(p[4],p[5],p[6],p[7]);
    asm volatile("s_waitcnt vmcnt(0)" ::: "memory");
    __syncthreads();

    bf16x8 av[4], bv[4];
#pragma unroll
    for (int i=0;i<4;i++)
      av[i] = *(const bf16x8*)&As[(wr*64 + i*16 + m)*32 + aq];
#pragma unroll
    for (int j=0;j<4;j++) {
      int n = wc*64 + j*16 + m;
      unsigned b0 = Bs[(q*4+0)*132 + n];
      unsigned b1 = Bs[(q*4+1)*132 + n];
      unsigned b2 = Bs[(q*4+2)*132 + n];
      unsigned b3 = Bs[(q*4+3)*132 + n];
      uint4 bb = make_uint4(b0,b1,b2,b3);
      bv[j] = *(const bf16x8*)&bb;
    }
#pragma unroll
    for (int i=0;i<4;i++)
#pragma unroll
      for (int j=0;j<4;j++)
        acc[i][j] = __builtin_amdgcn_mfma_f32_16x16x32_bf16(av[i], bv[j], acc[i][j], 0, 0, 0);
  }

#pragma unroll
  for (int i=0;i<4;i++) {
    int row0 = bm + wr*64 + i*16 + q*4;
#pragma unroll
    for (int j=0;j<4;j++) {
      int col = bn + wc*64 + j*16 + m;
      float bvv = barena ? toF(barena[biasOff + col]) : 0.f;
#pragma unroll
      for (int r=0;r<4;r++) {
        float v = acc[i][j][r] + bvv;
        if (act) v = gelu_f(v);
        if (rowscale) v *= rowscale[row0 + r];
        size_t idx = (size_t)(row0 + r)*N + col;
        if (accum) v += toF(C[idx]);
        C[idx] = __float2bfloat16(v);
      }
    }
  }
}

__global__ __launch_bounds__(256)
void gemm_k(const int* __restrict__ flag, const bf16* A,
            const void* W0, const void* W1, const void* W2, long eOff,
            const bf16* barena, int biasOff, int biasZStride,
            const float* rowscale, bf16* Cbase, long czStride,
            int N, int K, int accum, int act)
{
  __shared__ bf16 As[128*32];
  __shared__ unsigned Bs[16*132];
  int z = blockIdx.z;
  const void* Wp = (z==0) ? W0 : (z==1) ? W1 : W2;
  bf16* C = Cbase + (size_t)z * czStride;
  int bOff = biasOff + z*biasZStride;
  if (*flag) gemm_core<bf16>(As, Bs, A, (const bf16*)Wp + eOff, barena, bOff, rowscale, C, N, K, accum, act);
  else       gemm_core<float>(As, Bs, A, (const float*)Wp + eOff, barena, bOff, rowscale, C, N, K, accum, act);
}

// ---------------- V transpose: V(b,s,h,d) -> Vt(b,h,d,s) ----------------
__global__ __launch_bounds__(256)
void vtrans_kernel(const bf16* __restrict__ V, bf16* __restrict__ Vt)
{
  __shared__ bf16 t[64][72];     // 72 = 64 + 8 pad; rows 144 B (16B aligned)
  int bh = blockIdx.x;           // b*16 + h
  int sc_ = blockIdx.y;          // S/64 chunks
  int b = bh >> 4, h = bh & 15;
  int tid = threadIdx.x;
  {
    int s = tid >> 2, dd = (tid & 3) * 16;
    const bf16* src = &V[((size_t)b*Sq + sc_*64 + s)*Dq + h*64 + dd];
    uint4 a0 = *(const uint4*)src;
    uint4 a1 = *(const uint4*)(src + 8);
    *(uint4*)&t[s][dd]     = a0;
    *(uint4*)&t[s][dd + 8] = a1;
  }
  __syncthreads();
  {
    int d = tid >> 2, sp = (tid & 3) * 16;
    unsigned short buf[16];
#pragma unroll
    for (int e = 0; e < 16; e++) {
      bf16 v = t[sp + e][d];
      buf[e] = *(unsigned short*)&v;
    }
    bf16* dst = &Vt[((size_t)bh*DHq + d)*Sq + sc_*64 + sp];
    *(uint4*)dst       = *(uint4*)&buf[0];
    *(uint4*)(dst + 8) = *(uint4*)&buf[8];
  }
}

// ---------------- MFMA fused attention (dense / exact top-K sparse) ----------------
// One block = 16 query rows of one (b,h). O may alias Q.
template<int SPARSE>
__global__ __launch_bounds__(256, 4)
void attn_kernel(const bf16* __restrict__ Q, const bf16* __restrict__ K,
                 const bf16* __restrict__ Vt, bf16* __restrict__ O)
{
  const int PAST = 1032;                    // pa stride (bf16), row = 2064 B (16B-aligned)
  __shared__ bf16 pa[16*PAST];              // 33 KB: p in A-operand layout
  __shared__ float partA[64], partB[64];
  __shared__ int cntb[2][64];

  int blk = blockIdx.x;
  int rb = blk & 63;
  int h  = (blk >> 6) & 15;
  int b  = blk >> 10;
  int tid = threadIdx.x, lane = tid & 63, wave = tid >> 6;
  int m = lane & 15, q = lane >> 4;
  size_t base = ((size_t)b*Sq)*Dq + (size_t)h*DHq;
  int q0 = rb*16;

  // Q A-frags (k=0..31, 32..63)
  const bf16* qrow = &Q[base + (size_t)(q0+m)*Dq + q*8];
  bf16x8 aq0 = *(const bf16x8*)qrow;
  bf16x8 aq1 = *(const bf16x8*)(qrow + 32);

  // ---- QK^T: wave covers score cols [wave*256, wave*256+256), scores in regs ----
  f32x4 cc[16];
#pragma unroll
  for (int t = 0; t < 16; t++) {
    int j0 = wave*256 + t*16;
    const bf16* kp = &K[base + (size_t)(j0+m)*Dq + q*8];
    bf16x8 b0 = *(const bf16x8*)kp;
    bf16x8 b1 = *(const bf16x8*)(kp + 32);
    f32x4 c = {0.f,0.f,0.f,0.f};
    c = __builtin_amdgcn_mfma_f32_16x16x32_bf16(aq0, b0, c, 0, 0, 0);
    c = __builtin_amdgcn_mfma_f32_16x16x32_bf16(aq1, b1, c, 0, 0, 0);
#pragma unroll
    for (int r=0;r<4;r++) c[r] *= SCALEF;
    cc[t] = c;
  }

  // ---- sparse: exact kth-largest per row via bit-descend (float-domain compares) ----
  unsigned lo[4] = {0u,0u,0u,0u};
  if (SPARSE) {
    int cnt_cur[4] = {Sq, Sq, Sq, Sq};
    for (int bit = 31; bit >= 0; bit--) {
      int par = bit & 1;
      unsigned cand[4];
      float candf[4];
      int c4[4] = {0,0,0,0};
#pragma unroll
      for (int r=0;r<4;r++) {
        cand[r] = lo[r] | (1u << bit);
        candf[r] = thr_decode(cand[r]);
      }
#pragma unroll
      for (int t=0;t<16;t++)
#pragma unroll
        for (int r=0;r<4;r++) c4[r] += (cc[t][r] >= candf[r]) ? 1 : 0;
#pragma unroll
      for (int o=1;o<16;o<<=1)
#pragma unroll
        for (int r=0;r<4;r++) c4[r] += __shfl_xor(c4[r], o);
      if (m == 0) {
#pragma unroll
        for (int r=0;r<4;r++) cntb[par][wave*16 + q*4 + r] = c4[r];
      }
      __syncthreads();
      int done = 1;
#pragma unroll
      for (int r=0;r<4;r++) {
        int row = q*4 + r;
        int tot = cntb[par][row] + cntb[par][16+row] + cntb[par][32+row] + cntb[par][48+row];
        if (tot >= Kq) { lo[r] = cand[r]; cnt_cur[r] = tot; }
        done &= (cnt_cur[r] == Kq) ? 1 : 0;
      }
      done &= __shfl_xor(done, 16);
      done &= __shfl_xor(done, 32);
      if (done) break;
    }
  }

  // ---- row max (global max is always in top-K, so no mask needed) ----
  float mrow[4];
#pragma unroll
  for (int r=0;r<4;r++) {
    float v = -1e30f;
#pragma unroll
    for (int t=0;t<16;t++) v = fmaxf(v, cc[t][r]);
#pragma unroll
    for (int o=1;o<16;o<<=1) v = fmaxf(v, __shfl_xor(v, o));
    mrow[r] = v;
  }
  if (m == 0) {
#pragma unroll
    for (int r=0;r<4;r++) partA[wave*16 + q*4 + r] = mrow[r];
  }
  __syncthreads();
#pragma unroll
  for (int r=0;r<4;r++) {
    int row = q*4 + r;
    mrow[r] = fmaxf(fmaxf(partA[row], partA[16+row]), fmaxf(partA[32+row], partA[48+row]));
  }

  // ---- p = exp(s - m) (masked for sparse), write bf16 to pa, accumulate row sums ----
  float thrf[4];
  if (SPARSE) {
#pragma unroll
    for (int r=0;r<4;r++) {
      thrf[r] = (!(lo[r] & 0x80000000u) && lo[r] <= 0x007FFFFFu)
                    ? -INFINITY : thr_decode(lo[r]);
    }
  }
  float rsum[4] = {0.f,0.f,0.f,0.f};
#pragma unroll
  for (int t=0;t<16;t++) {
    int col = wave*256 + t*16 + m;
#pragma unroll
    for (int r=0;r<4;r++) {
      float p;
      if (SPARSE) p = (cc[t][r] >= thrf[r]) ? __expf(cc[t][r] - mrow[r]) : 0.f;
      else        p = __expf(cc[t][r] - mrow[r]);
      rsum[r] += p;
      pa[(q*4+r)*PAST + col] = __float2bfloat16(p);
    }
  }
#pragma unroll
  for (int r=0;r<4;r++)
#pragma unroll
    for (int o=1;o<16;o<<=1) rsum[r] += __shfl_xor(rsum[r], o);
  if (m == 0) {
#pragma unroll
    for (int r=0;r<4;r++) partB[wave*16 + q*4 + r] = rsum[r];
  }
  __syncthreads();   // also makes pa visible for PV
#pragma unroll
  for (int r=0;r<4;r++) {
    int row = q*4 + r;
    rsum[r] = partB[row] + partB[16+row] + partB[32+row] + partB[48+row];
    rsum[r] = fmaxf(rsum[r], 1e-30f);
  }

  // ---- PV: wave covers dh cols [wave*16, wave*16+16); B-frags from transposed V ----
  const bf16* vtp = &Vt[((size_t)(b*Hq + h)*DHq + wave*16 + m)*Sq];
  f32x4 oc = {0.f,0.f,0.f,0.f};
#pragma unroll 8
  for (int ks = 0; ks < 32; ks++) {
    bf16x8 af = *(const bf16x8*)&pa[m*PAST + ks*32 + q*8];
    bf16x8 bv = *(const bf16x8*)&vtp[ks*32 + q*8];
    oc = __builtin_amdgcn_mfma_f32_16x16x32_bf16(af, bv, oc, 0, 0, 0);
  }
#pragma unroll
  for (int r=0;r<4;r++) {
    O[base + (size_t)(q0 + q*4 + r)*Dq + wave*16 + m] = __float2bfloat16(oc[r] / rsum[r]);
  }
}

// ---------------- performer pass 1 (MFMA): kvT(d,m) = sum_s V(s,d) pk(s,m), z(m) = sum_s pk ----------------
// grid (32 bh, 8 m-groups of 32). Per block: full s-range, split 256 s per wave.
// pkT[m,s] = mfma(wfT rows m, K rows s); relu -> wave-private LDS; kvT += mfma(Vt rows d, p rows m).
__global__ __launch_bounds__(256)
void perf_kv_mfma(const bf16* __restrict__ Kb, const bf16* __restrict__ Vt,
                  const bf16* __restrict__ wft, bf16* __restrict__ kvb,
                  float* __restrict__ zg)
{
  __shared__ bf16 pbuf[4][32*40];       // p tiles, wave-private, stride 40 (80 B rows)
  __shared__ float kvred[4][64*32];     // 32 KB cross-wave reduce
  __shared__ float zred[4][32];

  int bh = blockIdx.x;                  // b*16 + h
  int mg = blockIdx.y;                  // m-group
  int b = bh >> 4, h = bh & 15;
  int tid = threadIdx.x, lane = tid & 63, wave = tid >> 6;
  int ml = lane & 15, q = lane >> 4;
  size_t kbase = ((size_t)b*Sq)*Dq + (size_t)h*DHq;
  const bf16* vtb = Vt + (size_t)bh*DHq*Sq;
  int sw0 = wave*256;
  bf16* pw = pbuf[wave];

  // wfT A-frags: rows m (2 tiles), k = d (2 chunks of 32)
  bf16x8 awf[2][2];
#pragma unroll
  for (int t=0;t<2;t++) {
    const bf16* p = &wft[(size_t)(mg*32 + t*16 + ml)*DHq + q*8];
    awf[t][0] = *(const bf16x8*)p;
    awf[t][1] = *(const bf16x8*)(p + 32);
  }

  f32x4 acc[4][2];                      // kvT: [d-tile][m-tile]
#pragma unroll
  for (int dt=0;dt<4;dt++)
#pragma unroll
    for (int t=0;t<2;t++) acc[dt][t] = (f32x4){0.f,0.f,0.f,0.f};
  float zacc[2][4] = {{0.f,0.f,0.f,0.f},{0.f,0.f,0.f,0.f}};

  for (int st = 0; st < 8; st++) {
    int s0 = sw0 + st*32;
    // pkT for this 32-s tile
    f32x4 pk[2][2];
#pragma unroll
    for (int sc=0;sc<2;sc++) {
      const bf16* kp = &Kb[kbase + (size_t)(s0 + sc*16 + ml)*Dq + q*8];
      bf16x8 b0 = *(const bf16x8*)kp;
      bf16x8 b1 = *(const bf16x8*)(kp + 32);
#pragma unroll
      for (int t=0;t<2;t++) {
        f32x4 c = (f32x4){0.f,0.f,0.f,0.f};
        c = __builtin_amdgcn_mfma_f32_16x16x32_bf16(awf[t][0], b0, c, 0, 0, 0);
        c = __builtin_amdgcn_mfma_f32_16x16x32_bf16(awf[t][1], b1, c, 0, 0, 0);
        pk[t][sc] = c;
      }
    }
    // relu, z accumulate, store p to wave-private LDS (row m, col s_local)
#pragma unroll
    for (int t=0;t<2;t++)
#pragma unroll
      for (int sc=0;sc<2;sc++)
#pragma unroll
        for (int r=0;r<4;r++) {
          float v = fmaxf(pk[t][sc][r], 0.f);
          zacc[t][r] += v;
          pw[(t*16 + q*4 + r)*40 + sc*16 + ml] = __float2bfloat16(v);
        }
    // kvT accumulate: A = Vt rows d, B = p rows m (k = 32 s)
#pragma unroll
    for (int dt=0;dt<4;dt++) {
      bf16x8 av = *(const bf16x8*)&vtb[(size_t)(dt*16 + ml)*Sq + s0 + q*8];
#pragma unroll
      for (int t=0;t<2;t++) {
        bf16x8 bp = *(const bf16x8*)&pw[(t*16 + ml)*40 + q*8];
        acc[dt][t] = __builtin_amdgcn_mfma_f32_16x16x32_bf16(av, bp, acc[dt][t], 0, 0, 0);
      }
    }
  }

  // stage kv partials + z partials, cross-wave reduce
#pragma unroll
  for (int dt=0;dt<4;dt++)
#pragma unroll
    for (int t=0;t<2;t++)
#pragma unroll
      for (int r=0;r<4;r++)
        kvred[wave][(dt*16 + q*4 + r)*32 + t*16 + ml] = acc[dt][t][r];
#pragma unroll
  for (int t=0;t<2;t++)
#pragma unroll
    for (int r=0;r<4;r++) {
      float v = zacc[t][r];
#pragma unroll
      for (int o=1;o<16;o<<=1) v += __shfl_xor(v, o);
      if (ml == 0) zred[wave][t*16 + q*4 + r] = v;
    }
  __syncthreads();
  for (int p = tid; p < 2048; p += 256) {
    float s = kvred[0][p] + kvred[1][p] + kvred[2][p] + kvred[3][p];
    int d = p >> 5, mloc = p & 31;
    kvb[(size_t)bh*(DHq*Mq) + d*Mq + mg*32 + mloc] = __float2bfloat16(s);
  }
  if (tid < 32) {
    float s = zred[0][tid] + zred[1][tid] + zred[2][tid] + zred[3][tid];
    zg[bh*Mq + mg*32 + tid] = s;
  }
}

// ---------------- performer pass 2 (MFMA): O = (pq @ kv) / (pq . z); O may alias Q ----------------
// grid = 32 bh * 16 s-chunks of 64. Wave owns s-tile of 16.
__global__ __launch_bounds__(256)
void perf_out_mfma(const bf16* __restrict__ Q, const bf16* __restrict__ wft,
                   const bf16* __restrict__ kvb, const float* __restrict__ zg,
                   bf16* __restrict__ O)
{
  const int PQST = 264;                 // pa2 stride (bf16): 528 B rows -> 2-way banks
  __shared__ bf16 pa2[64*PQST];         // ~33 KB
  __shared__ float zs[Mq];

  int blk = blockIdx.x;
  int sc_ = blk & 15;
  int bh  = blk >> 4;
  int b = bh >> 4, h = bh & 15;
  int tid = threadIdx.x, lane = tid & 63, wave = tid >> 6;
  int ml = lane & 15, q = lane >> 4;
  size_t base = ((size_t)b*Sq)*Dq + (size_t)h*DHq;
  int s0 = sc_*64;

  zs[tid] = zg[bh*Mq + tid];

  // Q A-frags: rows s (this wave's 16), k = d
  const bf16* qp = &Q[base + (size_t)(s0 + wave*16 + ml)*Dq + q*8];
  bf16x8 aq0 = *(const bf16x8*)qp;
  bf16x8 aq1 = *(const bf16x8*)(qp + 32);
  __syncthreads();                      // zs visible

  // pq[s, m] for all 256 m
  f32x4 pq[16];
#pragma unroll
  for (int mt=0;mt<16;mt++) {
    const bf16* wp = &wft[(size_t)(mt*16 + ml)*DHq + q*8];
    bf16x8 b0 = *(const bf16x8*)wp;
    bf16x8 b1 = *(const bf16x8*)(wp + 32);
    f32x4 c = (f32x4){0.f,0.f,0.f,0.f};
    c = __builtin_amdgcn_mfma_f32_16x16x32_bf16(aq0, b0, c, 0, 0, 0);
    c = __builtin_amdgcn_mfma_f32_16x16x32_bf16(aq1, b1, c, 0, 0, 0);
    pq[mt] = c;
  }

  // relu, den (f32, exact lane-layout match with num), stage pq -> LDS
  float den[4] = {1e-6f, 1e-6f, 1e-6f, 1e-6f};
#pragma unroll
  for (int mt=0;mt<16;mt++)
#pragma unroll
    for (int r=0;r<4;r++) {
      float v = fmaxf(pq[mt][r], 0.f);
      den[r] += v * zs[mt*16 + ml];
      pa2[(wave*16 + q*4 + r)*PQST + mt*16 + ml] = __float2bfloat16(v);
    }
#pragma unroll
  for (int r=0;r<4;r++)
#pragma unroll
    for (int o=1;o<16;o<<=1) den[r] += __shfl_xor(den[r], o);
  __syncthreads();

  // num[s, d] = mfma(pq rows s, kvT rows d) over k = 256 m
  const bf16* kvp = kvb + (size_t)bh*(DHq*Mq);
  f32x4 oc[4];
#pragma unroll
  for (int dt=0;dt<4;dt++) oc[dt] = (f32x4){0.f,0.f,0.f,0.f};
#pragma unroll
  for (int ks=0; ks<8; ks++) {
    bf16x8 ap = *(const bf16x8*)&pa2[(wave*16 + ml)*PQST + ks*32 + q*8];
#pragma unroll
    for (int dt=0;dt<4;dt++) {
      bf16x8 bk = *(const bf16x8*)&kvp[(size_t)(dt*16 + ml)*Mq + ks*32 + q*8];
      oc[dt] = __builtin_amdgcn_mfma_f32_16x16x32_bf16(ap, bk, oc[dt], 0, 0, 0);
    }
  }
#pragma unroll
  for (int dt=0;dt<4;dt++)
#pragma unroll
    for (int r=0;r<4;r++)
      O[base + (size_t)(s0 + wave*16 + q*4 + r)*Dq + dt*16 + ml] =
          __float2bfloat16(oc[dt][r] / den[r]);
}

// ---------------- LayerNorm ----------------
template<typename IT>
__device__ void ln_body(float* buf, float* red, const IT* __restrict__ xb,
                        const void* Ap, const void* Bp,
                        const IT* __restrict__ g, const IT* __restrict__ be,
                        void* out, int mode)
{
  int row = blockIdx.x;
  int tid = threadIdx.x;
  size_t off = (size_t)row*Dq;
  for (int dd = tid; dd < Dq; dd += 256) {
    float v;
    if (mode == 0)      v = toF(xb[off+dd]) + toF(((const bf16*)Ap)[off+dd]);
    else if (mode == 1) v = toF(((const bf16*)Ap)[off+dd]) + toF(((const bf16*)Bp)[off+dd]);
    else                v = toF(((const bf16*)Ap)[off+dd]);
    buf[dd] = v;
  }
  __syncthreads();
  float s = 0.f, q = 0.f;
  for (int dd = tid; dd < Dq; dd += 256) { float v = buf[dd]; s += v; q += v*v; }
#pragma unroll
  for (int o=32;o>=1;o>>=1) { s += __shfl_xor(s,o); q += __shfl_xor(q,o); }
  int w = tid >> 6;
  if ((tid & 63) == 0) { red[w] = s; red[4+w] = q; }
  __syncthreads();
  if (tid == 0) {
    float S1 = red[0]+red[1]+red[2]+red[3];
    float Q1 = red[4]+red[5]+red[6]+red[7];
    float mu = S1 / (float)Dq;
    float var = Q1 / (float)Dq - mu*mu;
    red[8] = mu; red[9] = rsqrtf(fmaxf(var, 0.f) + 1e-5f);
  }
  __syncthreads();
  float mu = red[8], inv = red[9];
  for (int dd = tid; dd < Dq; dd += 256) {
    float v = (buf[dd]-mu)*inv*toF(g[dd]) + toF(be[dd]);
    if (mode == 2) stF((IT*)out, off+dd, v);
    else           stF((bf16*)out, off+dd, v);
  }
}

__global__ __launch_bounds__(256)
void ln_kernel(const int* __restrict__ flag, const void* xb, const void* A, const void* Bv,
               const void* g, const void* be, void* out, int mode)
{
  __shared__ float buf[Dq];
  __shared__ float red[10];
  if (*flag) ln_body<bf16>(buf, red, (const bf16*)xb, A, Bv, (const bf16*)g, (const bf16*)be, out, mode);
  else       ln_body<float>(buf, red, (const float*)xb, A, Bv, (const float*)g, (const float*)be, out, mode);
}

// ---------------- avg over S ----------------
template<typename IT>
__device__ void avg_body(const IT* __restrict__ x, float* __restrict__ avg)
{
  int i = blockIdx.x*256 + threadIdx.x;
  if (i >= Bq*Dq) return;
  int b = i >> 10, dd = i & 1023;
  float s = 0.f;
  for (int ss = 0; ss < Sq; ss++) s += toF(x[((size_t)b*Sq+ss)*Dq + dd]);
  avg[i] = s * (1.0f/(float)Sq);
}
__global__ __launch_bounds__(256)
void avg_kernel(const int* __restrict__ flag, const void* x, float* avg)
{
  if (*flag) avg_body<bf16>((const bf16*)x, avg);
  else avg_body<float>((const float*)x, avg);
}

// ---------------- MoE router ----------------
template<typename IT>
__device__ void router_body(const IT* __restrict__ x, const IT* __restrict__ wr,
                            const IT* __restrict__ br, const float* __restrict__ cmb0,
                            float* __restrict__ gates_t)
{
  int row = blockIdx.x;
  int tid = threadIdx.x;
  size_t off = (size_t)row*Dq;
  float a0=0,a1=0,a2=0,a3=0;
  for (int dd = tid; dd < Dq; dd += 64) {
    float xv = toF(x[off+dd]);
    a0 += xv*toF(wr[dd*Eq+0]);
    a1 += xv*toF(wr[dd*Eq+1]);
    a2 += xv*toF(wr[dd*Eq+2]);
    a3 += xv*toF(wr[dd*Eq+3]);
  }
#pragma unroll
  for (int o=32;o>=1;o>>=1) {
    a0 += __shfl_xor(a0,o); a1 += __shfl_xor(a1,o);
    a2 += __shfl_xor(a2,o); a3 += __shfl_xor(a3,o);
  }
  if (tid == 0) {
    a0 += toF(br[0]); a1 += toF(br[1]); a2 += toF(br[2]); a3 += toF(br[3]);
    float m = fmaxf(fmaxf(a0,a1),fmaxf(a2,a3));
    float e0=__expf(a0-m), e1=__expf(a1-m), e2=__expf(a2-m), e3=__expf(a3-m);
    float inv = 1.f/(e0+e1+e2+e3);
    float sc = cmb0[row >> 10];
    gates_t[0*BSq+row]=e0*inv*sc; gates_t[1*BSq+row]=e1*inv*sc;
    gates_t[2*BSq+row]=e2*inv*sc; gates_t[3*BSq+row]=e3*inv*sc;
  }
}
__global__ __launch_bounds__(64)
void router_kernel(const int* __restrict__ flag, const void* x, const void* wr,
                   const void* br, const float* cmb0, float* gates_t)
{
  if (*flag) router_body<bf16>((const bf16*)x, (const bf16*)wr, (const bf16*)br, cmb0, gates_t);
  else       router_body<float>((const float*)x, (const float*)wr, (const float*)br, cmb0, gates_t);
}

// ---------------- tiny gate networks ----------------
template<typename IT>
__device__ void gates_body(float* g1, float* lg, float* ffnw, float* stg0, float* stg1, float* sffn,
    const float* __restrict__ avg,
    const IT* __restrict__ arg_w1, const IT* __restrict__ arg_b1,
    const IT* __restrict__ arg_w2, const IT* __restrict__ arg_b2,
    const IT* __restrict__ taa_wg, const IT* __restrict__ taa_bg,
    const IT* __restrict__ ag_w, const IT* __restrict__ ag_b,
    float* __restrict__ cmb0, float* __restrict__ rs_tg0,
    float* __restrict__ rs_tg1, float* __restrict__ rs_ffn)
{
  int tid = threadIdx.x;
  {
    int b = tid >> 7, j = tid & 127;
    float a = toF(arg_b1[j]);
    for (int dd = 0; dd < Dq; dd++) a += avg[b*Dq+dd]*toF(arg_w1[dd*GATEq+j]);
    g1[b*GATEq+j] = gelu_f(a);
  }
  __syncthreads();
  if (tid < 2) {
    float a = toF(arg_b2[1]);
    for (int j = 0; j < GATEq; j++) a += g1[tid*GATEq+j]*toF(arg_w2[j*2+1]);
    ffnw[tid] = 1.f/(1.f+__expf(-a));
  } else if (tid < 6) {
    int b = (tid-2)>>1, c = (tid-2)&1;
    float a = toF(taa_bg[c]);
    for (int dd = 0; dd < Dq; dd++) a += avg[b*Dq+dd]*toF(taa_wg[dd*2+c]);
    lg[b*2+c] = a;
  } else if (tid < 10) {
    int b = (tid-6)>>1, c = (tid-6)&1;
    float a = toF(ag_b[c]);
    for (int dd = 0; dd < Dq; dd++) a += avg[b*Dq+dd]*toF(ag_w[dd*2+c]);
    lg[4 + b*2+c] = a;
  }
  __syncthreads();
  if (tid < Bq) {
    int b = tid;
    float t0 = lg[b*2], t1 = lg[b*2+1];
    float m = fmaxf(t0,t1);
    float e0=__expf(t0-m), e1=__expf(t1-m), inv=1.f/(e0+e1);
    float tg0 = e0*inv, tg1 = e1*inv;
    float a0 = lg[4+b*2], a1l = lg[4+b*2+1];
    m = fmaxf(a0,a1l);
    float f0=__expf(a0-m), f1=__expf(a1l-m); inv = 1.f/(f0+f1);
    float ag0 = f0*inv, ag1 = f1*inv;
    cmb0[b] = ag0*DEPTHF;
    stg0[b] = tg0*ag1*DEPTHF;
    stg1[b] = tg1*ag1*DEPTHF;
    sffn[b] = ffnw[b]*DEPTHF;
  }
  __syncthreads();
  for (int i = tid; i < BSq; i += 256) {
    int b = i >> 10;
    rs_tg0[i] = stg0[b]; rs_tg1[i] = stg1[b]; rs_ffn[i] = sffn[b];
  }
}
__global__ __launch_bounds__(256)
void gates_small_kernel(const int* __restrict__ flag, const float* avg,
    const void* arg_w1, const void* arg_b1, const void* arg_w2, const void* arg_b2,
    const void* taa_wg, const void* taa_bg, const void* ag_w, const void* ag_b,
    float* cmb0, float* rs_tg0, float* rs_tg1, float* rs_ffn)
{
  __shared__ float g1[Bq*GATEq];
  __shared__ float lg[8];
  __shared__ float ffnw[2], stg0[2], stg1[2], sffn[2];
  if (*flag) gates_body<bf16>(g1, lg, ffnw, stg0, stg1, sffn, avg,
      (const bf16*)arg_w1,(const bf16*)arg_b1,(const bf16*)arg_w2,(const bf16*)arg_b2,
      (const bf16*)taa_wg,(const bf16*)taa_bg,(const bf16*)ag_w,(const bf16*)ag_b,
      cmb0, rs_tg0, rs_tg1, rs_ffn);
  else gates_body<float>(g1, lg, ffnw, stg0, stg1, sffn, avg,
      (const float*)arg_w1,(const float*)arg_b1,(const float*)arg_w2,(const float*)arg_b2,
      (const float*)taa_wg,(const float*)taa_bg,(const float*)ag_w,(const float*)ag_b,
      cmb0, rs_tg0, rs_tg1, rs_ffn);
}

extern "C" void kernel_launch(void* const* d_in, const int* in_sizes, int n_in,
                              void* d_out, int out_size, void* d_ws, size_t ws_size,
                              hipStream_t stream) {
  const void* x      = d_in[0];
  const void* arg_w1 = d_in[1];  const void* arg_b1 = d_in[2];
  const void* arg_w2 = d_in[3];  const void* arg_b2 = d_in[4];
  const void* moe_wr = d_in[5];  const void* moe_br = d_in[6];
  const void* moe_wq = d_in[7];  const void* moe_bq = d_in[8];
  const void* moe_wk = d_in[9];  const void* moe_bk = d_in[10];
  const void* moe_wv = d_in[11]; const void* moe_bv = d_in[12];
  const void* moe_wo = d_in[13]; const void* moe_bo = d_in[14];
  const void* sp_wq  = d_in[15]; const void* sp_bq  = d_in[16];
  const void* sp_wk  = d_in[17]; const void* sp_bk  = d_in[18];
  const void* sp_wv  = d_in[19]; const void* sp_bv  = d_in[20];
  const void* sp_wo  = d_in[21]; const void* sp_bo  = d_in[22];
  const void* pf_wq  = d_in[23]; const void* pf_bq  = d_in[24];
  const void* pf_wk  = d_in[25]; const void* pf_bk  = d_in[26];
  const void* pf_wv  = d_in[27]; const void* pf_bv  = d_in[28];
  const void* pf_wo  = d_in[29]; const void* pf_bo  = d_in[30];
  const void* pf_wf  = d_in[31];
  const void* taa_wg = d_in[32]; const void* taa_bg = d_in[33];
  const void* ag_w   = d_in[34]; const void* ag_b   = d_in[35];
  const void* ffn_w1 = d_in[36]; const void* ffn_b1 = d_in[37];
  const void* ffn_w2 = d_in[38]; const void* ffn_b2 = d_in[39];
  const void* n1_g   = d_in[40]; const void* n1_b   = d_in[41];
  const void* n2_g   = d_in[42]; const void* n2_b   = d_in[43];
  const void* n3_g   = d_in[44]; const void* n3_b   = d_in[45];

  char* w = (char*)d_ws;
  const size_t MB = 1024*1024;
  bf16* xb   = (bf16*)(w);            // [0,4)
  bf16* accb = (bf16*)(w + 4*MB);     // [4,8)
  bf16* Qb   = (bf16*)(w + 8*MB);     // [8,12)  (also attention O, in place)
  bf16* Kb   = (bf16*)(w + 12*MB);    // [12,16)
  bf16* Vb   = (bf16*)(w + 16*MB);    // [16,20)
  char* book = w + 20*MB;
  float* rs_tg0 = (float*)book;
  float* rs_tg1 = rs_tg0 + BSq;
  float* rs_ffn = rs_tg1 + BSq;
  float* cmb0   = rs_ffn + BSq;
  float* avgp   = cmb0 + 16;
  float* gates_t= avgp + Bq*Dq;
  float* zb     = gates_t + Eq*BSq;
  int*   dflag  = (int*)(zb + Bq*Hq*Mq);
  bf16*  barena = (bf16*)(dflag + 16);
  bf16*  wft    = barena + 29696;      // 16K bf16 (32 KB), 16B-aligned
  bf16*  Vt     = (bf16*)(w + 21*MB);  // [21,25) transposed V (b,h,d,s)
  bf16*  kvb    = (bf16*)w;            // performer kvT bf16 (1 MB), xb dead by then
  // FFN-phase aliases
  bf16* x1    = Vb;                    // [16,20)
  bf16* ffn_h = (bf16*)w;              // [0,16)
  bf16* tmpb  = (bf16*)(w + 21*MB);    // [21,25) over Vt (dead)
  bf16* x2    = (bf16*)w;              // [0,4)

  detect_kernel<<<1, 256, 0, stream>>>((const unsigned*)x, dflag);

  conv_x_kernel<<<BSq*Dq/1024, 256, 0, stream>>>(dflag, x, xb);
  pack_bias_kernel<<<1, 256, 0, stream>>>(dflag, barena,
      moe_bq, moe_bk, moe_bv, moe_bo, sp_bq, sp_bk, sp_bv, sp_bo,
      pf_bq, pf_bk, pf_bv, pf_bo, ffn_b1, ffn_b2);
  pack_wft_kernel<<<64, 256, 0, stream>>>(dflag, pf_wf, wft);
  avg_kernel<<<(Bq*Dq+255)/256, 256, 0, stream>>>(dflag, x, avgp);
  gates_small_kernel<<<1, 256, 0, stream>>>(dflag, avgp, arg_w1, arg_b1, arg_w2, arg_b2,
      taa_wg, taa_bg, ag_w, ag_b, cmb0, rs_tg0, rs_tg1, rs_ffn);
  router_kernel<<<BSq, 64, 0, stream>>>(dflag, x, moe_wr, moe_br, cmb0, gates_t);

  dim3 gQKV(16, 8, 3);
  dim3 gOP(16, 8, 1);
  dim3 gF1(16, 32, 1);
  dim3 gVT(Bq*Hq, Sq/64);
  int nAttnBlk = Bq*Hq*(Sq/16);
  long czQKV = (long)BSq*Dq;

  // ---- MoE expert attentions ----
  for (int e = 0; e < Eq; e++) {
    long eOff = (long)e*DD;
    gemm_k<<<gQKV, 256, 0, stream>>>(dflag, xb, moe_wq, moe_wk, moe_wv, eOff,
        barena, e*1024, 4096, nullptr, Qb, czQKV, Dq, Dq, 0, 0);
    vtrans_kernel<<<gVT, 256, 0, stream>>>(Vb, Vt);
    attn_kernel<0><<<nAttnBlk, 256, 0, stream>>>(Qb, Kb, Vt, Qb);
    gemm_k<<<gOP, 256, 0, stream>>>(dflag, Qb, moe_wo, moe_wo, moe_wo, eOff,
        barena, 12288 + e*1024, 0, gates_t + (size_t)e*BSq, accb, 0, Dq, Dq, (e>0)?1:0, 0);
  }

  // ---- sparse attention ----
  gemm_k<<<gQKV, 256, 0, stream>>>(dflag, xb, sp_wq, sp_wk, sp_wv, 0,
      barena, 16384, 1024, nullptr, Qb, czQKV, Dq, Dq, 0, 0);
  vtrans_kernel<<<gVT, 256, 0, stream>>>(Vb, Vt);
  attn_kernel<1><<<nAttnBlk, 256, 0, stream>>>(Qb, Kb, Vt, Qb);
  gemm_k<<<gOP, 256, 0, stream>>>(dflag, Qb, sp_wo, sp_wo, sp_wo, 0,
      barena, 19456, 0, rs_tg0, accb, 0, Dq, Dq, 1, 0);

  // ---- performer attention (MFMA both passes) ----
  gemm_k<<<gQKV, 256, 0, stream>>>(dflag, xb, pf_wq, pf_wk, pf_wv, 0,
      barena, 20480, 1024, nullptr, Qb, czQKV, Dq, Dq, 0, 0);
  vtrans_kernel<<<gVT, 256, 0, stream>>>(Vb, Vt);
  {
    dim3 gKV1(Bq*Hq, 8);
    perf_kv_mfma<<<gKV1, 256, 0, stream>>>(Kb, Vt, wft, kvb, zb);
  }
  perf_out_mfma<<<Bq*Hq*16, 256, 0, stream>>>(Qb, wft, kvb, zb, Qb);
  gemm_k<<<gOP, 256, 0, stream>>>(dflag, Qb, pf_wo, pf_wo, pf_wo, 0,
      barena, 23552, 0, rs_tg1, accb, 0, Dq, Dq, 1, 0);

  // ---- LN1: x + accb -> x1 ----
  ln_kernel<<<BSq, 256, 0, stream>>>(dflag, x, accb, nullptr, n1_g, n1_b, x1, 0);

  // ---- FFN ----
  gemm_k<<<gF1, 256, 0, stream>>>(dflag, x1, ffn_w1, ffn_w1, ffn_w1, 0,
      barena, 24576, 0, nullptr, ffn_h, 0, FFq, Dq, 0, 1);
  gemm_k<<<gOP, 256, 0, stream>>>(dflag, ffn_h, ffn_w2, ffn_w2, ffn_w2, 0,
      barena, 28672, 0, rs_ffn, tmpb, 0, Dq, FFq, 0, 0);

  // ---- LN2, LN3 ----
  ln_kernel<<<BSq, 256, 0, stream>>>(dflag, nullptr, x1, tmpb, n2_g, n2_b, x2, 1);
  ln_kernel<<<BSq, 256, 0, stream>>>(dflag, nullptr, x2, nullptr, n3_g, n3_b, d_out, 2);
}

// Round 3
// 1267.866 us; speedup vs baseline: 1.8599x; 1.5888x over previous
//
#include <hip/hip_runtime.h>
#include <hip/hip_bf16.h>
#include <math.h>

#define Bq 2
#define Sq 1024
#define Dq 1024
#define Hq 16
#define DHq 64
#define FFq 4096
#define Eq 4
#define Kq 64
#define Mq 256
#define GATEq 128
#define BSq (Bq*Sq)
#define DEPTHF 1.25f
#define SCALEF 0.125f
#define DD (Dq*Dq)
#define PLANE ((size_t)BSq*Dq)

typedef __hip_bfloat16 bf16;
typedef __attribute__((ext_vector_type(8))) __bf16 bf16x8;
typedef __attribute__((ext_vector_type(4))) float f32x4;

__device__ __forceinline__ float toF(float v){ return v; }
__device__ __forceinline__ float toF(bf16 v){ return __bfloat162float(v); }
__device__ __forceinline__ void stF(float* p, size_t i, float v){ p[i] = v; }
__device__ __forceinline__ void stF(bf16* p, size_t i, float v){ p[i] = __float2bfloat16(v); }
__device__ __forceinline__ float gelu_f(float x){
  const float c = 0.7978845608028654f;
  return 0.5f*x*(1.0f + tanhf(c*(x + 0.044715f*x*x*x)));
}
__device__ __forceinline__ unsigned short bfb(float f){
  bf16 h = __float2bfloat16(f);
  return *(unsigned short*)&h;
}
// inverse of the monotone uint map (uu = s<0 ? ~bits : bits|0x80000000)
__device__ __forceinline__ float thr_decode(unsigned c){
  unsigned ub = (c & 0x80000000u) ? (c & 0x7FFFFFFFu) : ~c;
  return __uint_as_float(ub);
}
// async global->LDS, 16B per lane; lds pointer must be wave-uniform (chunk base)
__device__ __forceinline__ void async_lds16(const void* g, void* lds) {
  __builtin_amdgcn_global_load_lds(
      (const __attribute__((address_space(1))) void*)(unsigned long long)(uintptr_t)g,
      (__attribute__((address_space(3))) void*)(unsigned)(uintptr_t)lds, 16, 0, 0);
}

// ---------------- dtype detector ----------------
__global__ __launch_bounds__(256)
void detect_kernel(const unsigned* __restrict__ xw, int* __restrict__ flag)
{
  __shared__ int cnt;
  if (threadIdx.x == 0) cnt = 0;
  __syncthreads();
  int c = 0;
  for (int i = threadIdx.x; i < 4096; i += 256) {
    unsigned e = (xw[i] >> 7) & 0xFFu;
    c += (e >= 0x70u && e <= 0x8Fu) ? 1 : 0;
  }
#pragma unroll
  for (int o = 32; o >= 1; o >>= 1) c += __shfl_xor(c, o);
  if ((threadIdx.x & 63) == 0) atomicAdd(&cnt, c);
  __syncthreads();
  if (threadIdx.x == 0) *flag = (cnt > 2048) ? 1 : 0;
}

// ---------------- convert x -> bf16 ----------------
__global__ __launch_bounds__(256)
void conv_x_kernel(const int* __restrict__ flag, const void* __restrict__ x, bf16* __restrict__ xb)
{
  int f = *flag;
  int i0 = (blockIdx.x*256 + threadIdx.x)*4;
  if (i0 >= BSq*Dq) return;
  if (f) {
    const bf16* s = (const bf16*)x;
#pragma unroll
    for (int k=0;k<4;k++) xb[i0+k] = s[i0+k];
  } else {
    const float* s = (const float*)x;
#pragma unroll
    for (int k=0;k<4;k++) xb[i0+k] = __float2bfloat16(s[i0+k]);
  }
}

// ---------------- pack all biases into bf16 arena ----------------
template<typename IT>
__device__ void packseg(bf16* dst, const IT* src, int len)
{
  for (int i = threadIdx.x; i < len; i += 256) dst[i] = __float2bfloat16(toF(src[i]));
}
__global__ __launch_bounds__(256)
void pack_bias_kernel(const int* __restrict__ flag, bf16* arena,
    const void* bq, const void* bk, const void* bv, const void* bo,
    const void* sq, const void* sk, const void* sv, const void* so,
    const void* pq, const void* pk, const void* pv, const void* po,
    const void* f1, const void* f2)
{
  int f = *flag;
  if (f) {
    packseg(arena+0,     (const bf16*)bq, 4096); packseg(arena+4096,  (const bf16*)bk, 4096);
    packseg(arena+8192,  (const bf16*)bv, 4096); packseg(arena+12288, (const bf16*)bo, 4096);
    packseg(arena+16384, (const bf16*)sq, 1024); packseg(arena+17408, (const bf16*)sk, 1024);
    packseg(arena+18432, (const bf16*)sv, 1024); packseg(arena+19456, (const bf16*)so, 1024);
    packseg(arena+20480, (const bf16*)pq, 1024); packseg(arena+21504, (const bf16*)pk, 1024);
    packseg(arena+22528, (const bf16*)pv, 1024); packseg(arena+23552, (const bf16*)po, 1024);
    packseg(arena+24576, (const bf16*)f1, 4096); packseg(arena+28672, (const bf16*)f2, 1024);
  } else {
    packseg(arena+0,     (const float*)bq, 4096); packseg(arena+4096,  (const float*)bk, 4096);
    packseg(arena+8192,  (const float*)bv, 4096); packseg(arena+12288, (const float*)bo, 4096);
    packseg(arena+16384, (const float*)sq, 1024); packseg(arena+17408, (const float*)sk, 1024);
    packseg(arena+18432, (const float*)sv, 1024); packseg(arena+19456, (const float*)so, 1024);
    packseg(arena+20480, (const float*)pq, 1024); packseg(arena+21504, (const float*)pk, 1024);
    packseg(arena+22528, (const float*)pv, 1024); packseg(arena+23552, (const float*)po, 1024);
    packseg(arena+24576, (const float*)f1, 4096); packseg(arena+28672, (const float*)f2, 1024);
  }
}

// ---------------- pack wf (DH x M) -> wfT (M x DH) bf16 ----------------
template<typename IT>
__device__ void packwft_body(const IT* __restrict__ wf, bf16* __restrict__ wft)
{
  int i = blockIdx.x*256 + threadIdx.x;
  if (i >= DHq*Mq) return;
  int d = i >> 8, m = i & 255;
  wft[m*DHq + d] = __float2bfloat16(toF(wf[(size_t)d*Mq + m]));
}
__global__ __launch_bounds__(256)
void pack_wft_kernel(const int* __restrict__ flag, const void* wf, bf16* wft)
{
  if (*flag) packwft_body<bf16>((const bf16*)wf, wft);
  else       packwft_body<float>((const float*)wf, wft);
}

// ---------------- pipelined MFMA GEMM core (2-phase, double-buffered LDS) ----------------
// C(2048xN) = act(A(2048xK) @ W(KxN) + bias) * rowscale     (bf16 out)
// or Cf(2048xN) = A @ W (raw f32 partial, split-K mode)
template<typename WT>
__device__ void gemm_core(bf16* As, unsigned* Bs,
    const bf16* __restrict__ A, int lda, const WT* __restrict__ W,
    const bf16* __restrict__ barena, int biasOff,
    const float* __restrict__ rowscale, bf16* __restrict__ C,
    float* __restrict__ Cf, int N, int K, int act)
{
  int tid = threadIdx.x;
  int lane = tid & 63, wave = tid >> 6;
  int wr = wave >> 1, wc = wave & 1;
  int bm = blockIdx.x * 128, bn = blockIdx.y * 128;

  int arow1 = wave*16 + (lane>>2);
  int akey = (arow1 >> 1) & 3;
  int acol = ((lane & 3) ^ akey) * 8;
  const bf16* aP1 = A + (size_t)(bm + arow1)*lda + acol;
  const bf16* aP2 = A + (size_t)(bm + arow1 + 64)*lda + acol;

  int kp = tid >> 4, nb8 = (tid & 15)*8;
  const WT* wP = W + (size_t)(2*kp)*N + bn + nb8;

  f32x4 acc[4][4];
#pragma unroll
  for (int i=0;i<4;i++)
#pragma unroll
    for (int j=0;j<4;j++) acc[i][j] = (f32x4){0.f,0.f,0.f,0.f};

  int m = lane & 15, q = lane >> 4;
  int akey2 = (m >> 1) & 3;
  int aq = (q ^ akey2) * 8;

  const int T = K >> 5;
  uint4 rwa, rwb, rwc, rwd;

  // prologue: stage tile 0
  async_lds16(aP1, As + wave*512);
  async_lds16(aP2, As + (wave+4)*512);
  aP1 += 32; aP2 += 32;
  if constexpr (sizeof(WT) == 2) {
    rwa = *(const uint4*)wP;
    rwb = *(const uint4*)(wP + N);
  } else {
    const float* f0 = (const float*)wP;
    const float* f1 = (const float*)(wP + N);
    rwa = *(const uint4*)f0; rwb = *(const uint4*)(f0+4);
    rwc = *(const uint4*)f1; rwd = *(const uint4*)(f1+4);
  }
  wP += (size_t)32*N;

  for (int t = 0; t < T; t++) {
    int cur = t & 1;
    // pack W(t) regs -> Bs[cur]
    unsigned p[8];
    if constexpr (sizeof(WT) == 2) {
      p[0] = (rwa.x & 0xFFFFu) | (rwb.x << 16);  p[1] = (rwa.x >> 16) | (rwb.x & 0xFFFF0000u);
      p[2] = (rwa.y & 0xFFFFu) | (rwb.y << 16);  p[3] = (rwa.y >> 16) | (rwb.y & 0xFFFF0000u);
      p[4] = (rwa.z & 0xFFFFu) | (rwb.z << 16);  p[5] = (rwa.z >> 16) | (rwb.z & 0xFFFF0000u);
      p[6] = (rwa.w & 0xFFFFu) | (rwb.w << 16);  p[7] = (rwa.w >> 16) | (rwb.w & 0xFFFF0000u);
    } else {
      p[0] = (unsigned)bfb(__uint_as_float(rwa.x)) | ((unsigned)bfb(__uint_as_float(rwc.x)) << 16);
      p[1] = (unsigned)bfb(__uint_as_float(rwa.y)) | ((unsigned)bfb(__uint_as_float(rwc.y)) << 16);
      p[2] = (unsigned)bfb(__uint_as_float(rwa.z)) | ((unsigned)bfb(__uint_as_float(rwc.z)) << 16);
      p[3] = (unsigned)bfb(__uint_as_float(rwa.w)) | ((unsigned)bfb(__uint_as_float(rwc.w)) << 16);
      p[4] = (unsigned)bfb(__uint_as_float(rwb.x)) | ((unsigned)bfb(__uint_as_float(rwd.x)) << 16);
      p[5] = (unsigned)bfb(__uint_as_float(rwb.y)) | ((unsigned)bfb(__uint_as_float(rwd.y)) << 16);
      p[6] = (unsigned)bfb(__uint_as_float(rwb.z)) | ((unsigned)bfb(__uint_as_float(rwd.z)) << 16);
      p[7] = (unsigned)bfb(__uint_as_float(rwb.w)) | ((unsigned)bfb(__uint_as_float(rwd.w)) << 16);
    }
    unsigned* bD = Bs + cur*2112 + kp*132 + nb8;
    *(uint4*)(bD)     = make_uint4(p[0],p[1],p[2],p[3]);
    *(uint4*)(bD + 4) = make_uint4(p[4],p[5],p[6],p[7]);
    asm volatile("s_waitcnt vmcnt(0)" ::: "memory");   // A(t) DMA arrived
    __syncthreads();
    // issue NEXT tile loads AFTER the barrier (so barrier drain can't serialize them;
    // they fly under this tile's MFMA phase)
    if (t + 1 < T) {
      bf16* asn = As + ((t+1)&1)*4096;
      async_lds16(aP1, asn + wave*512);
      async_lds16(aP2, asn + (wave+4)*512);
      aP1 += 32; aP2 += 32;
      if constexpr (sizeof(WT) == 2) {
        rwa = *(const uint4*)wP;
        rwb = *(const uint4*)(wP + N);
      } else {
        const float* f0 = (const float*)wP;
        const float* f1 = (const float*)(wP + N);
        rwa = *(const uint4*)f0; rwb = *(const uint4*)(f0+4);
        rwc = *(const uint4*)f1; rwd = *(const uint4*)(f1+4);
      }
      wP += (size_t)32*N;
    }
    const bf16* asc = As + cur*4096;
    const unsigned* bsc = Bs + cur*2112;
    bf16x8 av[4], bv[4];
#pragma unroll
    for (int i=0;i<4;i++)
      av[i] = *(const bf16x8*)&asc[(wr*64 + i*16 + m)*32 + aq];
#pragma unroll
    for (int j=0;j<4;j++) {
      int n = wc*64 + j*16 + m;
      unsigned b0 = bsc[(q*4+0)*132 + n];
      unsigned b1 = bsc[(q*4+1)*132 + n];
      unsigned b2 = bsc[(q*4+2)*132 + n];
      unsigned b3 = bsc[(q*4+3)*132 + n];
      uint4 bb = make_uint4(b0,b1,b2,b3);
      bv[j] = *(const bf16x8*)&bb;
    }
#pragma unroll
    for (int i=0;i<4;i++)
#pragma unroll
      for (int j=0;j<4;j++)
        acc[i][j] = __builtin_amdgcn_mfma_f32_16x16x32_bf16(av[i], bv[j], acc[i][j], 0, 0, 0);
  }

#pragma unroll
  for (int i=0;i<4;i++) {
    int row0 = bm + wr*64 + i*16 + q*4;
#pragma unroll
    for (int j=0;j<4;j++) {
      int col = bn + wc*64 + j*16 + m;
      float bvv = barena ? toF(barena[biasOff + col]) : 0.f;
#pragma unroll
      for (int r=0;r<4;r++) {
        size_t idx = (size_t)(row0 + r)*N + col;
        if (Cf) {
          Cf[idx] = acc[i][j][r];
        } else {
          float v = acc[i][j][r] + bvv;
          if (act) v = gelu_f(v);
          if (rowscale) v *= rowscale[row0 + r];
          C[idx] = __float2bfloat16(v);
        }
      }
    }
  }
}

// six-way z-batched GEMM (QKV pairs / all O-projections)
__global__ __launch_bounds__(256, 3)
void gemm6_k(const int* __restrict__ flag, const bf16* Abase, long az,
    const void* w0, const void* w1, const void* w2,
    const void* w3, const void* w4, const void* w5,
    long e0, long e1, long e2, long e3, long e4, long e5,
    int b0, int b1, int b2, int b3, int b4, int b5,
    const float* r0, const float* r1, const float* r2,
    const float* r3, const float* r4, const float* r5,
    bf16* c0, bf16* c1, bf16* c2, bf16* c3, bf16* c4, bf16* c5,
    const bf16* barena, int N, int K)
{
  __shared__ bf16 As[2*4096];
  __shared__ unsigned Bs[2*2112];
  int z = blockIdx.z;
  const void* Wp = (z==0)?w0:(z==1)?w1:(z==2)?w2:(z==3)?w3:(z==4)?w4:w5;
  long eo        = (z==0)?e0:(z==1)?e1:(z==2)?e2:(z==3)?e3:(z==4)?e4:e5;
  int bo         = (z==0)?b0:(z==1)?b1:(z==2)?b2:(z==3)?b3:(z==4)?b4:b5;
  const float* rs= (z==0)?r0:(z==1)?r1:(z==2)?r2:(z==3)?r3:(z==4)?r4:r5;
  bf16* C        = (z==0)?c0:(z==1)?c1:(z==2)?c2:(z==3)?c3:(z==4)?c4:c5;
  const bf16* A  = Abase + (size_t)z*az;
  if (*flag) gemm_core<bf16>(As, Bs, A, K, (const bf16*)Wp + eo, barena, bo, rs, C, nullptr, N, K, 0);
  else       gemm_core<float>(As, Bs, A, K, (const float*)Wp + eo, barena, bo, rs, C, nullptr, N, K, 0);
}

// single-matrix GEMM with optional split-K (z = K-chunk, f32 partial out)
__global__ __launch_bounds__(256, 3)
void gemm1_k(const int* __restrict__ flag, const bf16* A, int lda, const void* W,
             const bf16* barena, int biasOff, const float* rowscale,
             bf16* C, float* Cf, long cfz, int N, int K, int act, int kz)
{
  __shared__ bf16 As[2*4096];
  __shared__ unsigned Bs[2*2112];
  int z = blockIdx.z;
  const bf16* Az = A + (size_t)z*kz;
  long wo = (size_t)z*kz*N;
  float* Cfz = Cf ? (Cf + (size_t)z*cfz) : nullptr;
  if (*flag) gemm_core<bf16>(As, Bs, Az, lda, (const bf16*)W + wo, barena, biasOff, rowscale, C, Cfz, N, K, act);
  else       gemm_core<float>(As, Bs, Az, lda, (const float*)W + wo, barena, biasOff, rowscale, C, Cfz, N, K, act);
}

// ---------------- FFN2 split-K combine: out = (sum partials + bias) * rowscale ----------------
__global__ __launch_bounds__(256)
void combine_ffn2(const float* __restrict__ pf, const bf16* __restrict__ barena,
                  const float* __restrict__ rs, bf16* __restrict__ out)
{
  int i0 = (blockIdx.x*256 + threadIdx.x)*4;
  float4 s0 = *(const float4*)(pf + i0);
  float4 s1 = *(const float4*)(pf + PLANE + i0);
  float4 s2 = *(const float4*)(pf + 2*PLANE + i0);
  float4 s3 = *(const float4*)(pf + 3*PLANE + i0);
  int row = i0 >> 10, col = i0 & 1023;
  float r = rs[row];
  out[i0+0] = __float2bfloat16((s0.x+s1.x+s2.x+s3.x + toF(barena[28672+col+0])) * r);
  out[i0+1] = __float2bfloat16((s0.y+s1.y+s2.y+s3.y + toF(barena[28672+col+1])) * r);
  out[i0+2] = __float2bfloat16((s0.z+s1.z+s2.z+s3.z + toF(barena[28672+col+2])) * r);
  out[i0+3] = __float2bfloat16((s0.w+s1.w+s2.w+s3.w + toF(barena[28672+col+3])) * r);
}

// ---------------- V transpose: V(b,s,h,d) -> Vt(b,h,d,s), z-batched ----------------
__global__ __launch_bounds__(256)
void vtrans_kernel(const bf16* __restrict__ Vb, long vz, bf16* __restrict__ Vtb, long vtz)
{
  __shared__ bf16 t[64][72];
  const bf16* V = Vb + (size_t)blockIdx.z*vz;
  bf16* Vt = Vtb + (size_t)blockIdx.z*vtz;
  int bh = blockIdx.x;
  int sc_ = blockIdx.y;
  int b = bh >> 4, h = bh & 15;
  int tid = threadIdx.x;
  {
    int s = tid >> 2, dd = (tid & 3) * 16;
    const bf16* src = &V[((size_t)b*Sq + sc_*64 + s)*Dq + h*64 + dd];
    uint4 a0 = *(const uint4*)src;
    uint4 a1 = *(const uint4*)(src + 8);
    *(uint4*)&t[s][dd]     = a0;
    *(uint4*)&t[s][dd + 8] = a1;
  }
  __syncthreads();
  {
    int d = tid >> 2, sp = (tid & 3) * 16;
    unsigned short buf[16];
#pragma unroll
    for (int e = 0; e < 16; e++) {
      bf16 v = t[sp + e][d];
      buf[e] = *(unsigned short*)&v;
    }
    bf16* dst = &Vt[((size_t)bh*DHq + d)*Sq + sc_*64 + sp];
    *(uint4*)dst       = *(uint4*)&buf[0];
    *(uint4*)(dst + 8) = *(uint4*)&buf[8];
  }
}

// ---------------- MFMA fused attention (dense / exact top-K sparse) ----------------
template<int SPARSE>
__global__ __launch_bounds__(256, 4)
void attn_kernel(const bf16* __restrict__ Q, const bf16* __restrict__ K,
                 const bf16* __restrict__ Vt, bf16* __restrict__ O)
{
  const int PAST = 1032;
  __shared__ bf16 pa[16*PAST];
  __shared__ float partA[64], partB[64];
  __shared__ int cntb[2][64];

  int blk = blockIdx.x;
  int rb = blk & 63;
  int h  = (blk >> 6) & 15;
  int b  = blk >> 10;
  int tid = threadIdx.x, lane = tid & 63, wave = tid >> 6;
  int m = lane & 15, q = lane >> 4;
  size_t base = ((size_t)b*Sq)*Dq + (size_t)h*DHq;
  int q0 = rb*16;

  const bf16* qrow = &Q[base + (size_t)(q0+m)*Dq + q*8];
  bf16x8 aq0 = *(const bf16x8*)qrow;
  bf16x8 aq1 = *(const bf16x8*)(qrow + 32);

  f32x4 cc[16];
#pragma unroll
  for (int t = 0; t < 16; t++) {
    int j0 = wave*256 + t*16;
    const bf16* kp = &K[base + (size_t)(j0+m)*Dq + q*8];
    bf16x8 b0 = *(const bf16x8*)kp;
    bf16x8 b1 = *(const bf16x8*)(kp + 32);
    f32x4 c = {0.f,0.f,0.f,0.f};
    c = __builtin_amdgcn_mfma_f32_16x16x32_bf16(aq0, b0, c, 0, 0, 0);
    c = __builtin_amdgcn_mfma_f32_16x16x32_bf16(aq1, b1, c, 0, 0, 0);
#pragma unroll
    for (int r=0;r<4;r++) c[r] *= SCALEF;
    cc[t] = c;
  }

  unsigned lo[4] = {0u,0u,0u,0u};
  if (SPARSE) {
    int cnt_cur[4] = {Sq, Sq, Sq, Sq};
    for (int bit = 31; bit >= 0; bit--) {
      int par = bit & 1;
      unsigned cand[4];
      float candf[4];
      int c4[4] = {0,0,0,0};
#pragma unroll
      for (int r=0;r<4;r++) {
        cand[r] = lo[r] | (1u << bit);
        candf[r] = thr_decode(cand[r]);
      }
#pragma unroll
      for (int t=0;t<16;t++)
#pragma unroll
        for (int r=0;r<4;r++) c4[r] += (cc[t][r] >= candf[r]) ? 1 : 0;
#pragma unroll
      for (int o=1;o<16;o<<=1)
#pragma unroll
        for (int r=0;r<4;r++) c4[r] += __shfl_xor(c4[r], o);
      if (m == 0) {
#pragma unroll
        for (int r=0;r<4;r++) cntb[par][wave*16 + q*4 + r] = c4[r];
      }
      __syncthreads();
      int done = 1;
#pragma unroll
      for (int r=0;r<4;r++) {
        int row = q*4 + r;
        int tot = cntb[par][row] + cntb[par][16+row] + cntb[par][32+row] + cntb[par][48+row];
        if (tot >= Kq) { lo[r] = cand[r]; cnt_cur[r] = tot; }
        done &= (cnt_cur[r] == Kq) ? 1 : 0;
      }
      done &= __shfl_xor(done, 16);
      done &= __shfl_xor(done, 32);
      if (done) break;
    }
  }

  float mrow[4];
#pragma unroll
  for (int r=0;r<4;r++) {
    float v = -1e30f;
#pragma unroll
    for (int t=0;t<16;t++) v = fmaxf(v, cc[t][r]);
#pragma unroll
    for (int o=1;o<16;o<<=1) v = fmaxf(v, __shfl_xor(v, o));
    mrow[r] = v;
  }
  if (m == 0) {
#pragma unroll
    for (int r=0;r<4;r++) partA[wave*16 + q*4 + r] = mrow[r];
  }
  __syncthreads();
#pragma unroll
  for (int r=0;r<4;r++) {
    int row = q*4 + r;
    mrow[r] = fmaxf(fmaxf(partA[row], partA[16+row]), fmaxf(partA[32+row], partA[48+row]));
  }

  float thrf[4];
  if (SPARSE) {
#pragma unroll
    for (int r=0;r<4;r++) {
      thrf[r] = (!(lo[r] & 0x80000000u) && lo[r] <= 0x007FFFFFu)
                    ? -INFINITY : thr_decode(lo[r]);
    }
  }
  float rsum[4] = {0.f,0.f,0.f,0.f};
#pragma unroll
  for (int t=0;t<16;t++) {
    int col = wave*256 + t*16 + m;
#pragma unroll
    for (int r=0;r<4;r++) {
      float p;
      if (SPARSE) p = (cc[t][r] >= thrf[r]) ? __expf(cc[t][r] - mrow[r]) : 0.f;
      else        p = __expf(cc[t][r] - mrow[r]);
      rsum[r] += p;
      pa[(q*4+r)*PAST + col] = __float2bfloat16(p);
    }
  }
#pragma unroll
  for (int r=0;r<4;r++)
#pragma unroll
    for (int o=1;o<16;o<<=1) rsum[r] += __shfl_xor(rsum[r], o);
  if (m == 0) {
#pragma unroll
    for (int r=0;r<4;r++) partB[wave*16 + q*4 + r] = rsum[r];
  }
  __syncthreads();
#pragma unroll
  for (int r=0;r<4;r++) {
    int row = q*4 + r;
    rsum[r] = partB[row] + partB[16+row] + partB[32+row] + partB[48+row];
    rsum[r] = fmaxf(rsum[r], 1e-30f);
  }

  const bf16* vtp = &Vt[((size_t)(b*Hq + h)*DHq + wave*16 + m)*Sq];
  f32x4 oc = {0.f,0.f,0.f,0.f};
#pragma unroll 8
  for (int ks = 0; ks < 32; ks++) {
    bf16x8 af = *(const bf16x8*)&pa[m*PAST + ks*32 + q*8];
    bf16x8 bv = *(const bf16x8*)&vtp[ks*32 + q*8];
    oc = __builtin_amdgcn_mfma_f32_16x16x32_bf16(af, bv, oc, 0, 0, 0);
  }
#pragma unroll
  for (int r=0;r<4;r++) {
    O[base + (size_t)(q0 + q*4 + r)*Dq + wave*16 + m] = __float2bfloat16(oc[r] / rsum[r]);
  }
}

// ---------------- performer pass 1 (MFMA) ----------------
__global__ __launch_bounds__(256)
void perf_kv_mfma(const bf16* __restrict__ Kb, const bf16* __restrict__ Vt,
                  const bf16* __restrict__ wft, bf16* __restrict__ kvb,
                  float* __restrict__ zg)
{
  __shared__ bf16 pbuf[4][32*40];
  __shared__ float kvred[4][64*32];
  __shared__ float zred[4][32];

  int bh = blockIdx.x;
  int mg = blockIdx.y;
  int b = bh >> 4, h = bh & 15;
  int tid = threadIdx.x, lane = tid & 63, wave = tid >> 6;
  int ml = lane & 15, q = lane >> 4;
  size_t kbase = ((size_t)b*Sq)*Dq + (size_t)h*DHq;
  const bf16* vtb = Vt + (size_t)bh*DHq*Sq;
  int sw0 = wave*256;
  bf16* pw = pbuf[wave];

  bf16x8 awf[2][2];
#pragma unroll
  for (int t=0;t<2;t++) {
    const bf16* p = &wft[(size_t)(mg*32 + t*16 + ml)*DHq + q*8];
    awf[t][0] = *(const bf16x8*)p;
    awf[t][1] = *(const bf16x8*)(p + 32);
  }

  f32x4 acc[4][2];
#pragma unroll
  for (int dt=0;dt<4;dt++)
#pragma unroll
    for (int t=0;t<2;t++) acc[dt][t] = (f32x4){0.f,0.f,0.f,0.f};
  float zacc[2][4] = {{0.f,0.f,0.f,0.f},{0.f,0.f,0.f,0.f}};

  for (int st = 0; st < 8; st++) {
    int s0 = sw0 + st*32;
    f32x4 pk[2][2];
#pragma unroll
    for (int sc=0;sc<2;sc++) {
      const bf16* kp = &Kb[kbase + (size_t)(s0 + sc*16 + ml)*Dq + q*8];
      bf16x8 b0 = *(const bf16x8*)kp;
      bf16x8 b1 = *(const bf16x8*)(kp + 32);
#pragma unroll
      for (int t=0;t<2;t++) {
        f32x4 c = (f32x4){0.f,0.f,0.f,0.f};
        c = __builtin_amdgcn_mfma_f32_16x16x32_bf16(awf[t][0], b0, c, 0, 0, 0);
        c = __builtin_amdgcn_mfma_f32_16x16x32_bf16(awf[t][1], b1, c, 0, 0, 0);
        pk[t][sc] = c;
      }
    }
#pragma unroll
    for (int t=0;t<2;t++)
#pragma unroll
      for (int sc=0;sc<2;sc++)
#pragma unroll
        for (int r=0;r<4;r++) {
          float v = fmaxf(pk[t][sc][r], 0.f);
          zacc[t][r] += v;
          pw[(t*16 + q*4 + r)*40 + sc*16 + ml] = __float2bfloat16(v);
        }
#pragma unroll
    for (int dt=0;dt<4;dt++) {
      bf16x8 av = *(const bf16x8*)&vtb[(size_t)(dt*16 + ml)*Sq + s0 + q*8];
#pragma unroll
      for (int t=0;t<2;t++) {
        bf16x8 bp = *(const bf16x8*)&pw[(t*16 + ml)*40 + q*8];
        acc[dt][t] = __builtin_amdgcn_mfma_f32_16x16x32_bf16(av, bp, acc[dt][t], 0, 0, 0);
      }
    }
  }

#pragma unroll
  for (int dt=0;dt<4;dt++)
#pragma unroll
    for (int t=0;t<2;t++)
#pragma unroll
      for (int r=0;r<4;r++)
        kvred[wave][(dt*16 + q*4 + r)*32 + t*16 + ml] = acc[dt][t][r];
#pragma unroll
  for (int t=0;t<2;t++)
#pragma unroll
    for (int r=0;r<4;r++) {
      float v = zacc[t][r];
#pragma unroll
      for (int o=1;o<16;o<<=1) v += __shfl_xor(v, o);
      if (ml == 0) zred[wave][t*16 + q*4 + r] = v;
    }
  __syncthreads();
  for (int p = tid; p < 2048; p += 256) {
    float s = kvred[0][p] + kvred[1][p] + kvred[2][p] + kvred[3][p];
    int d = p >> 5, mloc = p & 31;
    kvb[(size_t)bh*(DHq*Mq) + d*Mq + mg*32 + mloc] = __float2bfloat16(s);
  }
  if (tid < 32) {
    float s = zred[0][tid] + zred[1][tid] + zred[2][tid] + zred[3][tid];
    zg[bh*Mq + mg*32 + tid] = s;
  }
}

// ---------------- performer pass 2 (MFMA) ----------------
__global__ __launch_bounds__(256)
void perf_out_mfma(const bf16* __restrict__ Q, const bf16* __restrict__ wft,
                   const bf16* __restrict__ kvb, const float* __restrict__ zg,
                   bf16* __restrict__ O)
{
  const int PQST = 264;
  __shared__ bf16 pa2[64*PQST];
  __shared__ float zs[Mq];

  int blk = blockIdx.x;
  int sc_ = blk & 15;
  int bh  = blk >> 4;
  int b = bh >> 4, h = bh & 15;
  int tid = threadIdx.x, lane = tid & 63, wave = tid >> 6;
  int ml = lane & 15, q = lane >> 4;
  size_t base = ((size_t)b*Sq)*Dq + (size_t)h*DHq;
  int s0 = sc_*64;

  zs[tid] = zg[bh*Mq + tid];

  const bf16* qp = &Q[base + (size_t)(s0 + wave*16 + ml)*Dq + q*8];
  bf16x8 aq0 = *(const bf16x8*)qp;
  bf16x8 aq1 = *(const bf16x8*)(qp + 32);
  __syncthreads();

  f32x4 pq[16];
#pragma unroll
  for (int mt=0;mt<16;mt++) {
    const bf16* wp = &wft[(size_t)(mt*16 + ml)*DHq + q*8];
    bf16x8 b0 = *(const bf16x8*)wp;
    bf16x8 b1 = *(const bf16x8*)(wp + 32);
    f32x4 c = (f32x4){0.f,0.f,0.f,0.f};
    c = __builtin_amdgcn_mfma_f32_16x16x32_bf16(aq0, b0, c, 0, 0, 0);
    c = __builtin_amdgcn_mfma_f32_16x16x32_bf16(aq1, b1, c, 0, 0, 0);
    pq[mt] = c;
  }

  float den[4] = {1e-6f, 1e-6f, 1e-6f, 1e-6f};
#pragma unroll
  for (int mt=0;mt<16;mt++)
#pragma unroll
    for (int r=0;r<4;r++) {
      float v = fmaxf(pq[mt][r], 0.f);
      den[r] += v * zs[mt*16 + ml];
      pa2[(wave*16 + q*4 + r)*PQST + mt*16 + ml] = __float2bfloat16(v);
    }
#pragma unroll
  for (int r=0;r<4;r++)
#pragma unroll
    for (int o=1;o<16;o<<=1) den[r] += __shfl_xor(den[r], o);
  __syncthreads();

  const bf16* kvp = kvb + (size_t)bh*(DHq*Mq);
  f32x4 oc[4];
#pragma unroll
  for (int dt=0;dt<4;dt++) oc[dt] = (f32x4){0.f,0.f,0.f,0.f};
#pragma unroll
  for (int ks=0; ks<8; ks++) {
    bf16x8 ap = *(const bf16x8*)&pa2[(wave*16 + ml)*PQST + ks*32 + q*8];
#pragma unroll
    for (int dt=0;dt<4;dt++) {
      bf16x8 bk = *(const bf16x8*)&kvp[(size_t)(dt*16 + ml)*Mq + ks*32 + q*8];
      oc[dt] = __builtin_amdgcn_mfma_f32_16x16x32_bf16(ap, bk, oc[dt], 0, 0, 0);
    }
  }
#pragma unroll
  for (int dt=0;dt<4;dt++)
#pragma unroll
    for (int r=0;r<4;r++)
      O[base + (size_t)(s0 + wave*16 + q*4 + r)*Dq + dt*16 + ml] =
          __float2bfloat16(oc[dt][r] / den[r]);
}

// ---------------- LayerNorm ----------------
// mode 0: x + A            mode 1: A + B        mode 2: A only
// mode 3: x + sum of 6 bf16 planes at A (stride PLANE)
template<typename IT>
__device__ void ln_body(float* buf, float* red, const IT* __restrict__ xb,
                        const void* Ap, const void* Bp,
                        const IT* __restrict__ g, const IT* __restrict__ be,
                        void* out, int mode)
{
  int row = blockIdx.x;
  int tid = threadIdx.x;
  size_t off = (size_t)row*Dq;
  for (int dd = tid; dd < Dq; dd += 256) {
    float v;
    if (mode == 0)      v = toF(xb[off+dd]) + toF(((const bf16*)Ap)[off+dd]);
    else if (mode == 1) v = toF(((const bf16*)Ap)[off+dd]) + toF(((const bf16*)Bp)[off+dd]);
    else if (mode == 3) {
      const bf16* P = (const bf16*)Ap;
      v = toF(xb[off+dd]);
#pragma unroll
      for (int p=0;p<6;p++) v += toF(P[(size_t)p*PLANE + off + dd]);
    }
    else                v = toF(((const bf16*)Ap)[off+dd]);
    buf[dd] = v;
  }
  __syncthreads();
  float s = 0.f, q = 0.f;
  for (int dd = tid; dd < Dq; dd += 256) { float v = buf[dd]; s += v; q += v*v; }
#pragma unroll
  for (int o=32;o>=1;o>>=1) { s += __shfl_xor(s,o); q += __shfl_xor(q,o); }
  int w = tid >> 6;
  if ((tid & 63) == 0) { red[w] = s; red[4+w] = q; }
  __syncthreads();
  if (tid == 0) {
    float S1 = red[0]+red[1]+red[2]+red[3];
    float Q1 = red[4]+red[5]+red[6]+red[7];
    float mu = S1 / (float)Dq;
    float var = Q1 / (float)Dq - mu*mu;
    red[8] = mu; red[9] = rsqrtf(fmaxf(var, 0.f) + 1e-5f);
  }
  __syncthreads();
  float mu = red[8], inv = red[9];
  for (int dd = tid; dd < Dq; dd += 256) {
    float v = (buf[dd]-mu)*inv*toF(g[dd]) + toF(be[dd]);
    if (mode == 2) stF((IT*)out, off+dd, v);
    else           stF((bf16*)out, off+dd, v);
  }
}

__global__ __launch_bounds__(256)
void ln_kernel(const int* __restrict__ flag, const void* xb, const void* A, const void* Bv,
               const void* g, const void* be, void* out, int mode)
{
  __shared__ float buf[Dq];
  __shared__ float red[10];
  if (*flag) ln_body<bf16>(buf, red, (const bf16*)xb, A, Bv, (const bf16*)g, (const bf16*)be, out, mode);
  else       ln_body<float>(buf, red, (const float*)xb, A, Bv, (const float*)g, (const float*)be, out, mode);
}

// ---------------- avg over S ----------------
template<typename IT>
__device__ void avg_body(const IT* __restrict__ x, float* __restrict__ avg)
{
  int i = blockIdx.x*256 + threadIdx.x;
  if (i >= Bq*Dq) return;
  int b = i >> 10, dd = i & 1023;
  float s = 0.f;
  for (int ss = 0; ss < Sq; ss++) s += toF(x[((size_t)b*Sq+ss)*Dq + dd]);
  avg[i] = s * (1.0f/(float)Sq);
}
__global__ __launch_bounds__(256)
void avg_kernel(const int* __restrict__ flag, const void* x, float* avg)
{
  if (*flag) avg_body<bf16>((const bf16*)x, avg);
  else avg_body<float>((const float*)x, avg);
}

// ---------------- MoE router ----------------
template<typename IT>
__device__ void router_body(const IT* __restrict__ x, const IT* __restrict__ wr,
                            const IT* __restrict__ br, const float* __restrict__ cmb0,
                            float* __restrict__ gates_t)
{
  int row = blockIdx.x;
  int tid = threadIdx.x;
  size_t off = (size_t)row*Dq;
  float a0=0,a1=0,a2=0,a3=0;
  for (int dd = tid; dd < Dq; dd += 64) {
    float xv = toF(x[off+dd]);
    a0 += xv*toF(wr[dd*Eq+0]);
    a1 += xv*toF(wr[dd*Eq+1]);
    a2 += xv*toF(wr[dd*Eq+2]);
    a3 += xv*toF(wr[dd*Eq+3]);
  }
#pragma unroll
  for (int o=32;o>=1;o>>=1) {
    a0 += __shfl_xor(a0,o); a1 += __shfl_xor(a1,o);
    a2 += __shfl_xor(a2,o); a3 += __shfl_xor(a3,o);
  }
  if (tid == 0) {
    a0 += toF(br[0]); a1 += toF(br[1]); a2 += toF(br[2]); a3 += toF(br[3]);
    float m = fmaxf(fmaxf(a0,a1),fmaxf(a2,a3));
    float e0=__expf(a0-m), e1=__expf(a1-m), e2=__expf(a2-m), e3=__expf(a3-m);
    float inv = 1.f/(e0+e1+e2+e3);
    float sc = cmb0[row >> 10];
    gates_t[0*BSq+row]=e0*inv*sc; gates_t[1*BSq+row]=e1*inv*sc;
    gates_t[2*BSq+row]=e2*inv*sc; gates_t[3*BSq+row]=e3*inv*sc;
  }
}
__global__ __launch_bounds__(64)
void router_kernel(const int* __restrict__ flag, const void* x, const void* wr,
                   const void* br, const float* cmb0, float* gates_t)
{
  if (*flag) router_body<bf16>((const bf16*)x, (const bf16*)wr, (const bf16*)br, cmb0, gates_t);
  else       router_body<float>((const float*)x, (const float*)wr, (const float*)br, cmb0, gates_t);
}

// ---------------- tiny gate networks ----------------
template<typename IT>
__device__ void gates_body(float* g1, float* lg, float* ffnw, float* stg0, float* stg1, float* sffn,
    const float* __restrict__ avg,
    const IT* __restrict__ arg_w1, const IT* __restrict__ arg_b1,
    const IT* __restrict__ arg_w2, const IT* __restrict__ arg_b2,
    const IT* __restrict__ taa_wg, const IT* __restrict__ taa_bg,
    const IT* __restrict__ ag_w, const IT* __restrict__ ag_b,
    float* __restrict__ cmb0, float* __restrict__ rs_tg0,
    float* __restrict__ rs_tg1, float* __restrict__ rs_ffn)
{
  int tid = threadIdx.x;
  {
    int b = tid >> 7, j = tid & 127;
    float a = toF(arg_b1[j]);
    for (int dd = 0; dd < Dq; dd++) a += avg[b*Dq+dd]*toF(arg_w1[dd*GATEq+j]);
    g1[b*GATEq+j] = gelu_f(a);
  }
  __syncthreads();
  if (tid < 2) {
    float a = toF(arg_b2[1]);
    for (int j = 0; j < GATEq; j++) a += g1[tid*GATEq+j]*toF(arg_w2[j*2+1]);
    ffnw[tid] = 1.f/(1.f+__expf(-a));
  } else if (tid < 6) {
    int b = (tid-2)>>1, c = (tid-2)&1;
    float a = toF(taa_bg[c]);
    for (int dd = 0; dd < Dq; dd++) a += avg[b*Dq+dd]*toF(taa_wg[dd*2+c]);
    lg[b*2+c] = a;
  } else if (tid < 10) {
    int b = (tid-6)>>1, c = (tid-6)&1;
    float a = toF(ag_b[c]);
    for (int dd = 0; dd < Dq; dd++) a += avg[b*Dq+dd]*toF(ag_w[dd*2+c]);
    lg[4 + b*2+c] = a;
  }
  __syncthreads();
  if (tid < Bq) {
    int b = tid;
    float t0 = lg[b*2], t1 = lg[b*2+1];
    float m = fmaxf(t0,t1);
    float e0=__expf(t0-m), e1=__expf(t1-m), inv=1.f/(e0+e1);
    float tg0 = e0*inv, tg1 = e1*inv;
    float a0 = lg[4+b*2], a1l = lg[4+b*2+1];
    m = fmaxf(a0,a1l);
    float f0=__expf(a0-m), f1=__expf(a1l-m); inv = 1.f/(f0+f1);
    float ag0 = f0*inv, ag1 = f1*inv;
    cmb0[b] = ag0*DEPTHF;
    stg0[b] = tg0*ag1*DEPTHF;
    stg1[b] = tg1*ag1*DEPTHF;
    sffn[b] = ffnw[b]*DEPTHF;
  }
  __syncthreads();
  for (int i = tid; i < BSq; i += 256) {
    int b = i >> 10;
    rs_tg0[i] = stg0[b]; rs_tg1[i] = stg1[b]; rs_ffn[i] = sffn[b];
  }
}
__global__ __launch_bounds__(256)
void gates_small_kernel(const int* __restrict__ flag, const float* avg,
    const void* arg_w1, const void* arg_b1, const void* arg_w2, const void* arg_b2,
    const void* taa_wg, const void* taa_bg, const void* ag_w, const void* ag_b,
    float* cmb0, float* rs_tg0, float* rs_tg1, float* rs_ffn)
{
  __shared__ float g1[Bq*GATEq];
  __shared__ float lg[8];
  __shared__ float ffnw[2], stg0[2], stg1[2], sffn[2];
  if (*flag) gates_body<bf16>(g1, lg, ffnw, stg0, stg1, sffn, avg,
      (const bf16*)arg_w1,(const bf16*)arg_b1,(const bf16*)arg_w2,(const bf16*)arg_b2,
      (const bf16*)taa_wg,(const bf16*)taa_bg,(const bf16*)ag_w,(const bf16*)ag_b,
      cmb0, rs_tg0, rs_tg1, rs_ffn);
  else gates_body<float>(g1, lg, ffnw, stg0, stg1, sffn, avg,
      (const float*)arg_w1,(const float*)arg_b1,(const float*)arg_w2,(const float*)arg_b2,
      (const float*)taa_wg,(const float*)taa_bg,(const float*)ag_w,(const float*)ag_b,
      cmb0, rs_tg0, rs_tg1, rs_ffn);
}

extern "C" void kernel_launch(void* const* d_in, const int* in_sizes, int n_in,
                              void* d_out, int out_size, void* d_ws, size_t ws_size,
                              hipStream_t stream) {
  const void* x      = d_in[0];
  const void* arg_w1 = d_in[1];  const void* arg_b1 = d_in[2];
  const void* arg_w2 = d_in[3];  const void* arg_b2 = d_in[4];
  const void* moe_wr = d_in[5];  const void* moe_br = d_in[6];
  const void* moe_wq = d_in[7];  const void* moe_bq = d_in[8];
  const void* moe_wk = d_in[9];  const void* moe_bk = d_in[10];
  const void* moe_wv = d_in[11]; const void* moe_bv = d_in[12];
  const void* moe_wo = d_in[13]; const void* moe_bo = d_in[14];
  const void* sp_wq  = d_in[15]; const void* sp_bq  = d_in[16];
  const void* sp_wk  = d_in[17]; const void* sp_bk  = d_in[18];
  const void* sp_wv  = d_in[19]; const void* sp_bv  = d_in[20];
  const void* sp_wo  = d_in[21]; const void* sp_bo  = d_in[22];
  const void* pf_wq  = d_in[23]; const void* pf_bq  = d_in[24];
  const void* pf_wk  = d_in[25]; const void* pf_bk  = d_in[26];
  const void* pf_wv  = d_in[27]; const void* pf_bv  = d_in[28];
  const void* pf_wo  = d_in[29]; const void* pf_bo  = d_in[30];
  const void* pf_wf  = d_in[31];
  const void* taa_wg = d_in[32]; const void* taa_bg = d_in[33];
  const void* ag_w   = d_in[34]; const void* ag_b   = d_in[35];
  const void* ffn_w1 = d_in[36]; const void* ffn_b1 = d_in[37];
  const void* ffn_w2 = d_in[38]; const void* ffn_b2 = d_in[39];
  const void* n1_g   = d_in[40]; const void* n1_b   = d_in[41];
  const void* n2_g   = d_in[42]; const void* n2_b   = d_in[43];
  const void* n3_g   = d_in[44]; const void* n3_b   = d_in[45];

  char* w = (char*)d_ws;
  const size_t MB = 1024*1024;
  // phase 1 (attention):
  bf16* xb  = (bf16*)w;                 // [0,4)
  bf16* Qp  = (bf16*)(w + 4*MB);        // [4,28)  6 Q planes (attn out in place)
  bf16* KV  = (bf16*)(w + 28*MB);       // [28,44) K0,V0,K1,V1
  bf16* Vt  = (bf16*)(w + 44*MB);       // [44,52) Vt0,Vt1
  bf16* Pp  = (bf16*)(w + 28*MB);       // [28,52) 6 O-proj planes (over KV/Vt, dead)
  // phase 2 (FFN):
  bf16* x1    = (bf16*)(w + 4*MB);      // [4,8)
  bf16* ffn_h = (bf16*)(w + 8*MB);      // [8,24)
  float* partF= (float*)(w + 24*MB);    // [24,56) 4 f32 partial planes
  bf16* tmpb  = (bf16*)w;               // [0,4)  (xb dead)
  bf16* x2    = (bf16*)w;               // LN2 writes in place over tmpb (row-safe)
  // bookkeeping:
  char* book = w + 56*MB;
  float* rs_tg0 = (float*)book;
  float* rs_tg1 = rs_tg0 + BSq;
  float* rs_ffn = rs_tg1 + BSq;
  float* cmb0   = rs_ffn + BSq;
  float* avgp   = cmb0 + 16;
  float* gates_t= avgp + Bq*Dq;
  float* zb     = gates_t + Eq*BSq;
  int*   dflag  = (int*)(zb + Bq*Hq*Mq);
  bf16*  barena = (bf16*)(dflag + 16);
  bf16*  wft    = barena + 29696;
  bf16*  kvb    = (bf16*)(w + 57*MB);   // [57,58) performer kvT

  detect_kernel<<<1, 256, 0, stream>>>((const unsigned*)x, dflag);
  conv_x_kernel<<<BSq*Dq/1024, 256, 0, stream>>>(dflag, x, xb);
  pack_bias_kernel<<<1, 256, 0, stream>>>(dflag, barena,
      moe_bq, moe_bk, moe_bv, moe_bo, sp_bq, sp_bk, sp_bv, sp_bo,
      pf_bq, pf_bk, pf_bv, pf_bo, ffn_b1, ffn_b2);
  pack_wft_kernel<<<64, 256, 0, stream>>>(dflag, pf_wf, wft);
  avg_kernel<<<(Bq*Dq+255)/256, 256, 0, stream>>>(dflag, x, avgp);
  gates_small_kernel<<<1, 256, 0, stream>>>(dflag, avgp, arg_w1, arg_b1, arg_w2, arg_b2,
      taa_wg, taa_bg, ag_w, ag_b, cmb0, rs_tg0, rs_tg1, rs_ffn);
  router_kernel<<<BSq, 64, 0, stream>>>(dflag, x, moe_wr, moe_br, cmb0, gates_t);

  dim3 g6(16, 8, 6);
  dim3 gVT(Bq*Hq, Sq/64, 2);
  int nAttnBlk = Bq*Hq*(Sq/16);

  // ---- MoE expert attentions, paired ----
  for (int p = 0; p < 2; p++) {
    int e0 = 2*p, e1 = 2*p + 1;
    gemm6_k<<<g6, 256, 0, stream>>>(dflag, xb, 0L,
        moe_wq, moe_wk, moe_wv, moe_wq, moe_wk, moe_wv,
        (long)e0*DD, (long)e0*DD, (long)e0*DD, (long)e1*DD, (long)e1*DD, (long)e1*DD,
        e0*1024, e0*1024+4096, e0*1024+8192, e1*1024, e1*1024+4096, e1*1024+8192,
        nullptr, nullptr, nullptr, nullptr, nullptr, nullptr,
        Qp + (size_t)e0*PLANE, KV, KV + PLANE,
        Qp + (size_t)e1*PLANE, KV + 2*PLANE, KV + 3*PLANE,
        barena, Dq, Dq);
    vtrans_kernel<<<gVT, 256, 0, stream>>>(KV + PLANE, (long)(2*PLANE), Vt, (long)PLANE);
    attn_kernel<0><<<nAttnBlk, 256, 0, stream>>>(Qp + (size_t)e0*PLANE, KV, Vt, Qp + (size_t)e0*PLANE);
    attn_kernel<0><<<nAttnBlk, 256, 0, stream>>>(Qp + (size_t)e1*PLANE, KV + 2*PLANE, Vt + PLANE, Qp + (size_t)e1*PLANE);
  }

  // ---- sparse + performer QKV, paired ----
  gemm6_k<<<g6, 256, 0, stream>>>(dflag, xb, 0L,
      sp_wq, sp_wk, sp_wv, pf_wq, pf_wk, pf_wv,
      0L, 0L, 0L, 0L, 0L, 0L,
      16384, 17408, 18432, 20480, 21504, 22528,
      nullptr, nullptr, nullptr, nullptr, nullptr, nullptr,
      Qp + 4*PLANE, KV, KV + PLANE,
      Qp + 5*PLANE, KV + 2*PLANE, KV + 3*PLANE,
      barena, Dq, Dq);
  vtrans_kernel<<<gVT, 256, 0, stream>>>(KV + PLANE, (long)(2*PLANE), Vt, (long)PLANE);
  attn_kernel<1><<<nAttnBlk, 256, 0, stream>>>(Qp + 4*PLANE, KV, Vt, Qp + 4*PLANE);
  {
    dim3 gKV1(Bq*Hq, 8);
    perf_kv_mfma<<<gKV1, 256, 0, stream>>>(KV + 2*PLANE, Vt + PLANE, wft, kvb, zb);
  }
  perf_out_mfma<<<Bq*Hq*16, 256, 0, stream>>>(Qp + 5*PLANE, wft, kvb, zb, Qp + 5*PLANE);

  // ---- all six O-projections in one launch, each to its own plane ----
  gemm6_k<<<g6, 256, 0, stream>>>(dflag, Qp, (long)PLANE,
      moe_wo, moe_wo, moe_wo, moe_wo, sp_wo, pf_wo,
      0L, (long)DD, (long)2*DD, (long)3*DD, 0L, 0L,
      12288, 13312, 14336, 15360, 19456, 23552,
      gates_t, gates_t + BSq, gates_t + 2*BSq, gates_t + 3*BSq, rs_tg0, rs_tg1,
      Pp, Pp + PLANE, Pp + 2*PLANE, Pp + 3*PLANE, Pp + 4*PLANE, Pp + 5*PLANE,
      barena, Dq, Dq);

  // ---- LN1: x + sum of 6 planes -> x1 ----
  ln_kernel<<<BSq, 256, 0, stream>>>(dflag, x, Pp, nullptr, n1_g, n1_b, x1, 3);

  // ---- FFN ----
  gemm1_k<<<dim3(16, 32, 1), 256, 0, stream>>>(dflag, x1, Dq, ffn_w1,
      barena, 24576, nullptr, ffn_h, nullptr, 0L, FFq, Dq, 1, 0);
  gemm1_k<<<dim3(16, 8, 4), 256, 0, stream>>>(dflag, ffn_h, FFq, ffn_w2,
      nullptr, 0, nullptr, nullptr, partF, (long)PLANE, Dq, 1024, 0, 1024);
  combine_ffn2<<<BSq*Dq/1024, 256, 0, stream>>>(partF, barena, rs_ffn, tmpb);

  // ---- LN2, LN3 ----
  ln_kernel<<<BSq, 256, 0, stream>>>(dflag, nullptr, x1, tmpb, n2_g, n2_b, x2, 1);
  ln_kernel<<<BSq, 256, 0, stream>>>(dflag, nullptr, x2, nullptr, n3_g, n3_b, d_out, 2);
}

// Round 4
// 1095.076 us; speedup vs baseline: 2.1534x; 1.1578x over previous
//
#include <hip/hip_runtime.h>
#include <hip/hip_bf16.h>
#include <math.h>

#define Bq 2
#define Sq 1024
#define Dq 1024
#define Hq 16
#define DHq 64
#define FFq 4096
#define Eq 4
#define Kq 64
#define Mq 256
#define GATEq 128
#define BSq (Bq*Sq)
#define DEPTHF 1.25f
#define SCALEF 0.125f
#define DD (Dq*Dq)
#define PLANE ((size_t)BSq*Dq)

typedef __hip_bfloat16 bf16;
typedef __attribute__((ext_vector_type(8))) __bf16 bf16x8;
typedef __attribute__((ext_vector_type(4))) float f32x4;

__device__ __forceinline__ float toF(float v){ return v; }
__device__ __forceinline__ float toF(bf16 v){ return __bfloat162float(v); }
__device__ __forceinline__ void stF(float* p, size_t i, float v){ p[i] = v; }
__device__ __forceinline__ void stF(bf16* p, size_t i, float v){ p[i] = __float2bfloat16(v); }
__device__ __forceinline__ float gelu_f(float x){
  const float c = 0.7978845608028654f;
  return 0.5f*x*(1.0f + tanhf(c*(x + 0.044715f*x*x*x)));
}
__device__ __forceinline__ unsigned short bfb(float f){
  bf16 h = __float2bfloat16(f);
  return *(unsigned short*)&h;
}
// inverse of the monotone uint map (uu = s<0 ? ~bits : bits|0x80000000)
__device__ __forceinline__ float thr_decode(unsigned c){
  unsigned ub = (c & 0x80000000u) ? (c & 0x7FFFFFFFu) : ~c;
  return __uint_as_float(ub);
}
// async global->LDS, 16B per lane; lds pointer must be wave-uniform (chunk base)
__device__ __forceinline__ void async_lds16(const void* g, void* lds) {
  __builtin_amdgcn_global_load_lds(
      (const __attribute__((address_space(1))) void*)(unsigned long long)(uintptr_t)g,
      (__attribute__((address_space(3))) void*)(unsigned)(uintptr_t)lds, 16, 0, 0);
}

// ---------------- dtype detector ----------------
__global__ __launch_bounds__(256)
void detect_kernel(const unsigned* __restrict__ xw, int* __restrict__ flag)
{
  __shared__ int cnt;
  if (threadIdx.x == 0) cnt = 0;
  __syncthreads();
  int c = 0;
  for (int i = threadIdx.x; i < 4096; i += 256) {
    unsigned e = (xw[i] >> 7) & 0xFFu;
    c += (e >= 0x70u && e <= 0x8Fu) ? 1 : 0;
  }
#pragma unroll
  for (int o = 32; o >= 1; o >>= 1) c += __shfl_xor(c, o);
  if ((threadIdx.x & 63) == 0) atomicAdd(&cnt, c);
  __syncthreads();
  if (threadIdx.x == 0) *flag = (cnt > 2048) ? 1 : 0;
}

// ---------------- convert x -> bf16 ----------------
__global__ __launch_bounds__(256)
void conv_x_kernel(const int* __restrict__ flag, const void* __restrict__ x, bf16* __restrict__ xb)
{
  int f = *flag;
  int i0 = (blockIdx.x*256 + threadIdx.x)*4;
  if (i0 >= BSq*Dq) return;
  if (f) {
    const bf16* s = (const bf16*)x;
#pragma unroll
    for (int k=0;k<4;k++) xb[i0+k] = s[i0+k];
  } else {
    const float* s = (const float*)x;
#pragma unroll
    for (int k=0;k<4;k++) xb[i0+k] = __float2bfloat16(s[i0+k]);
  }
}

// ---------------- pack all biases into bf16 arena ----------------
template<typename IT>
__device__ void packseg(bf16* dst, const IT* src, int len)
{
  for (int i = threadIdx.x; i < len; i += 256) dst[i] = __float2bfloat16(toF(src[i]));
}
__global__ __launch_bounds__(256)
void pack_bias_kernel(const int* __restrict__ flag, bf16* arena,
    const void* bq, const void* bk, const void* bv, const void* bo,
    const void* sq, const void* sk, const void* sv, const void* so,
    const void* pq, const void* pk, const void* pv, const void* po,
    const void* f1, const void* f2)
{
  int f = *flag;
  if (f) {
    packseg(arena+0,     (const bf16*)bq, 4096); packseg(arena+4096,  (const bf16*)bk, 4096);
    packseg(arena+8192,  (const bf16*)bv, 4096); packseg(arena+12288, (const bf16*)bo, 4096);
    packseg(arena+16384, (const bf16*)sq, 1024); packseg(arena+17408, (const bf16*)sk, 1024);
    packseg(arena+18432, (const bf16*)sv, 1024); packseg(arena+19456, (const bf16*)so, 1024);
    packseg(arena+20480, (const bf16*)pq, 1024); packseg(arena+21504, (const bf16*)pk, 1024);
    packseg(arena+22528, (const bf16*)pv, 1024); packseg(arena+23552, (const bf16*)po, 1024);
    packseg(arena+24576, (const bf16*)f1, 4096); packseg(arena+28672, (const bf16*)f2, 1024);
  } else {
    packseg(arena+0,     (const float*)bq, 4096); packseg(arena+4096,  (const float*)bk, 4096);
    packseg(arena+8192,  (const float*)bv, 4096); packseg(arena+12288, (const float*)bo, 4096);
    packseg(arena+16384, (const float*)sq, 1024); packseg(arena+17408, (const float*)sk, 1024);
    packseg(arena+18432, (const float*)sv, 1024); packseg(arena+19456, (const float*)so, 1024);
    packseg(arena+20480, (const float*)pq, 1024); packseg(arena+21504, (const float*)pk, 1024);
    packseg(arena+22528, (const float*)pv, 1024); packseg(arena+23552, (const float*)po, 1024);
    packseg(arena+24576, (const float*)f1, 4096); packseg(arena+28672, (const float*)f2, 1024);
  }
}

// ---------------- pack wf (DH x M) -> wfT (M x DH) bf16 ----------------
template<typename IT>
__device__ void packwft_body(const IT* __restrict__ wf, bf16* __restrict__ wft)
{
  int i = blockIdx.x*256 + threadIdx.x;
  if (i >= DHq*Mq) return;
  int d = i >> 8, m = i & 255;
  wft[m*DHq + d] = __float2bfloat16(toF(wf[(size_t)d*Mq + m]));
}
__global__ __launch_bounds__(256)
void pack_wft_kernel(const int* __restrict__ flag, const void* wf, bf16* wft)
{
  if (*flag) packwft_body<bf16>((const bf16*)wf, wft);
  else       packwft_body<float>((const float*)wf, wft);
}

// ---------------- pipelined MFMA GEMM core (2-phase, double-buffered LDS) ----------------
template<typename WT>
__device__ void gemm_core(bf16* As, unsigned* Bs,
    const bf16* __restrict__ A, int lda, const WT* __restrict__ W,
    const bf16* __restrict__ barena, int biasOff,
    const float* __restrict__ rowscale, bf16* __restrict__ C,
    float* __restrict__ Cf, int N, int K, int act)
{
  int tid = threadIdx.x;
  int lane = tid & 63, wave = tid >> 6;
  int wr = wave >> 1, wc = wave & 1;
  int bm = blockIdx.x * 128, bn = blockIdx.y * 128;

  int arow1 = wave*16 + (lane>>2);
  int akey = (arow1 >> 1) & 3;
  int acol = ((lane & 3) ^ akey) * 8;
  const bf16* aP1 = A + (size_t)(bm + arow1)*lda + acol;
  const bf16* aP2 = A + (size_t)(bm + arow1 + 64)*lda + acol;

  int kp = tid >> 4, nb8 = (tid & 15)*8;
  const WT* wP = W + (size_t)(2*kp)*N + bn + nb8;

  f32x4 acc[4][4];
#pragma unroll
  for (int i=0;i<4;i++)
#pragma unroll
    for (int j=0;j<4;j++) acc[i][j] = (f32x4){0.f,0.f,0.f,0.f};

  int m = lane & 15, q = lane >> 4;
  int akey2 = (m >> 1) & 3;
  int aq = (q ^ akey2) * 8;

  const int T = K >> 5;
  uint4 rwa, rwb, rwc, rwd;

  async_lds16(aP1, As + wave*512);
  async_lds16(aP2, As + (wave+4)*512);
  aP1 += 32; aP2 += 32;
  if constexpr (sizeof(WT) == 2) {
    rwa = *(const uint4*)wP;
    rwb = *(const uint4*)(wP + N);
  } else {
    const float* f0 = (const float*)wP;
    const float* f1 = (const float*)(wP + N);
    rwa = *(const uint4*)f0; rwb = *(const uint4*)(f0+4);
    rwc = *(const uint4*)f1; rwd = *(const uint4*)(f1+4);
  }
  wP += (size_t)32*N;

  for (int t = 0; t < T; t++) {
    int cur = t & 1;
    unsigned p[8];
    if constexpr (sizeof(WT) == 2) {
      p[0] = (rwa.x & 0xFFFFu) | (rwb.x << 16);  p[1] = (rwa.x >> 16) | (rwb.x & 0xFFFF0000u);
      p[2] = (rwa.y & 0xFFFFu) | (rwb.y << 16);  p[3] = (rwa.y >> 16) | (rwb.y & 0xFFFF0000u);
      p[4] = (rwa.z & 0xFFFFu) | (rwb.z << 16);  p[5] = (rwa.z >> 16) | (rwb.z & 0xFFFF0000u);
      p[6] = (rwa.w & 0xFFFFu) | (rwb.w << 16);  p[7] = (rwa.w >> 16) | (rwb.w & 0xFFFF0000u);
    } else {
      p[0] = (unsigned)bfb(__uint_as_float(rwa.x)) | ((unsigned)bfb(__uint_as_float(rwc.x)) << 16);
      p[1] = (unsigned)bfb(__uint_as_float(rwa.y)) | ((unsigned)bfb(__uint_as_float(rwc.y)) << 16);
      p[2] = (unsigned)bfb(__uint_as_float(rwa.z)) | ((unsigned)bfb(__uint_as_float(rwc.z)) << 16);
      p[3] = (unsigned)bfb(__uint_as_float(rwa.w)) | ((unsigned)bfb(__uint_as_float(rwc.w)) << 16);
      p[4] = (unsigned)bfb(__uint_as_float(rwb.x)) | ((unsigned)bfb(__uint_as_float(rwd.x)) << 16);
      p[5] = (unsigned)bfb(__uint_as_float(rwb.y)) | ((unsigned)bfb(__uint_as_float(rwd.y)) << 16);
      p[6] = (unsigned)bfb(__uint_as_float(rwb.z)) | ((unsigned)bfb(__uint_as_float(rwd.z)) << 16);
      p[7] = (unsigned)bfb(__uint_as_float(rwb.w)) | ((unsigned)bfb(__uint_as_float(rwd.w)) << 16);
    }
    unsigned* bD = Bs + cur*2112 + kp*132 + nb8;
    *(uint4*)(bD)     = make_uint4(p[0],p[1],p[2],p[3]);
    *(uint4*)(bD + 4) = make_uint4(p[4],p[5],p[6],p[7]);
    asm volatile("s_waitcnt vmcnt(0)" ::: "memory");
    __syncthreads();
    if (t + 1 < T) {
      bf16* asn = As + ((t+1)&1)*4096;
      async_lds16(aP1, asn + wave*512);
      async_lds16(aP2, asn + (wave+4)*512);
      aP1 += 32; aP2 += 32;
      if constexpr (sizeof(WT) == 2) {
        rwa = *(const uint4*)wP;
        rwb = *(const uint4*)(wP + N);
      } else {
        const float* f0 = (const float*)wP;
        const float* f1 = (const float*)(wP + N);
        rwa = *(const uint4*)f0; rwb = *(const uint4*)(f0+4);
        rwc = *(const uint4*)f1; rwd = *(const uint4*)(f1+4);
      }
      wP += (size_t)32*N;
    }
    const bf16* asc = As + cur*4096;
    const unsigned* bsc = Bs + cur*2112;
    bf16x8 av[4], bv[4];
#pragma unroll
    for (int i=0;i<4;i++)
      av[i] = *(const bf16x8*)&asc[(wr*64 + i*16 + m)*32 + aq];
#pragma unroll
    for (int j=0;j<4;j++) {
      int n = wc*64 + j*16 + m;
      unsigned b0 = bsc[(q*4+0)*132 + n];
      unsigned b1 = bsc[(q*4+1)*132 + n];
      unsigned b2 = bsc[(q*4+2)*132 + n];
      unsigned b3 = bsc[(q*4+3)*132 + n];
      uint4 bb = make_uint4(b0,b1,b2,b3);
      bv[j] = *(const bf16x8*)&bb;
    }
#pragma unroll
    for (int i=0;i<4;i++)
#pragma unroll
      for (int j=0;j<4;j++)
        acc[i][j] = __builtin_amdgcn_mfma_f32_16x16x32_bf16(av[i], bv[j], acc[i][j], 0, 0, 0);
  }

#pragma unroll
  for (int i=0;i<4;i++) {
    int row0 = bm + wr*64 + i*16 + q*4;
#pragma unroll
    for (int j=0;j<4;j++) {
      int col = bn + wc*64 + j*16 + m;
      float bvv = barena ? toF(barena[biasOff + col]) : 0.f;
#pragma unroll
      for (int r=0;r<4;r++) {
        size_t idx = (size_t)(row0 + r)*N + col;
        if (Cf) {
          Cf[idx] = acc[i][j][r];
        } else {
          float v = acc[i][j][r] + bvv;
          if (act) v = gelu_f(v);
          if (rowscale) v *= rowscale[row0 + r];
          C[idx] = __float2bfloat16(v);
        }
      }
    }
  }
}

// six-way z-batched GEMM (QKV pairs / all O-projections)
__global__ __launch_bounds__(256, 3)
void gemm6_k(const int* __restrict__ flag, const bf16* Abase, long az,
    const void* w0, const void* w1, const void* w2,
    const void* w3, const void* w4, const void* w5,
    long e0, long e1, long e2, long e3, long e4, long e5,
    int b0, int b1, int b2, int b3, int b4, int b5,
    const float* r0, const float* r1, const float* r2,
    const float* r3, const float* r4, const float* r5,
    bf16* c0, bf16* c1, bf16* c2, bf16* c3, bf16* c4, bf16* c5,
    const bf16* barena, int N, int K)
{
  __shared__ bf16 As[2*4096];
  __shared__ unsigned Bs[2*2112];
  int z = blockIdx.z;
  const void* Wp = (z==0)?w0:(z==1)?w1:(z==2)?w2:(z==3)?w3:(z==4)?w4:w5;
  long eo        = (z==0)?e0:(z==1)?e1:(z==2)?e2:(z==3)?e3:(z==4)?e4:e5;
  int bo         = (z==0)?b0:(z==1)?b1:(z==2)?b2:(z==3)?b3:(z==4)?b4:b5;
  const float* rs= (z==0)?r0:(z==1)?r1:(z==2)?r2:(z==3)?r3:(z==4)?r4:r5;
  bf16* C        = (z==0)?c0:(z==1)?c1:(z==2)?c2:(z==3)?c3:(z==4)?c4:c5;
  const bf16* A  = Abase + (size_t)z*az;
  if (*flag) gemm_core<bf16>(As, Bs, A, K, (const bf16*)Wp + eo, barena, bo, rs, C, nullptr, N, K, 0);
  else       gemm_core<float>(As, Bs, A, K, (const float*)Wp + eo, barena, bo, rs, C, nullptr, N, K, 0);
}

// single-matrix GEMM with optional split-K (z = K-chunk, f32 partial out)
__global__ __launch_bounds__(256, 3)
void gemm1_k(const int* __restrict__ flag, const bf16* A, int lda, const void* W,
             const bf16* barena, int biasOff, const float* rowscale,
             bf16* C, float* Cf, long cfz, int N, int K, int act, int kz)
{
  __shared__ bf16 As[2*4096];
  __shared__ unsigned Bs[2*2112];
  int z = blockIdx.z;
  const bf16* Az = A + (size_t)z*kz;
  long wo = (size_t)z*kz*N;
  float* Cfz = Cf ? (Cf + (size_t)z*cfz) : nullptr;
  if (*flag) gemm_core<bf16>(As, Bs, Az, lda, (const bf16*)W + wo, barena, biasOff, rowscale, C, Cfz, N, K, act);
  else       gemm_core<float>(As, Bs, Az, lda, (const float*)W + wo, barena, biasOff, rowscale, C, Cfz, N, K, act);
}

// ---------------- FFN2 split-K combine: out = (sum partials + bias) * rowscale ----------------
__global__ __launch_bounds__(256)
void combine_ffn2(const float* __restrict__ pf, const bf16* __restrict__ barena,
                  const float* __restrict__ rs, bf16* __restrict__ out)
{
  int i0 = (blockIdx.x*256 + threadIdx.x)*4;
  float4 s0 = *(const float4*)(pf + i0);
  float4 s1 = *(const float4*)(pf + PLANE + i0);
  float4 s2 = *(const float4*)(pf + 2*PLANE + i0);
  float4 s3 = *(const float4*)(pf + 3*PLANE + i0);
  int row = i0 >> 10, col = i0 & 1023;
  float r = rs[row];
  out[i0+0] = __float2bfloat16((s0.x+s1.x+s2.x+s3.x + toF(barena[28672+col+0])) * r);
  out[i0+1] = __float2bfloat16((s0.y+s1.y+s2.y+s3.y + toF(barena[28672+col+1])) * r);
  out[i0+2] = __float2bfloat16((s0.z+s1.z+s2.z+s3.z + toF(barena[28672+col+2])) * r);
  out[i0+3] = __float2bfloat16((s0.w+s1.w+s2.w+s3.w + toF(barena[28672+col+3])) * r);
}

// ---------------- V transpose: V(b,s,h,d) -> Vt(b,h,d,s), z-batched ----------------
__global__ __launch_bounds__(256)
void vtrans_kernel(const bf16* __restrict__ Vb, long vz, bf16* __restrict__ Vtb, long vtz)
{
  __shared__ bf16 t[64][72];
  const bf16* V = Vb + (size_t)blockIdx.z*vz;
  bf16* Vt = Vtb + (size_t)blockIdx.z*vtz;
  int bh = blockIdx.x;
  int sc_ = blockIdx.y;
  int b = bh >> 4, h = bh & 15;
  int tid = threadIdx.x;
  {
    int s = tid >> 2, dd = (tid & 3) * 16;
    const bf16* src = &V[((size_t)b*Sq + sc_*64 + s)*Dq + h*64 + dd];
    uint4 a0 = *(const uint4*)src;
    uint4 a1 = *(const uint4*)(src + 8);
    *(uint4*)&t[s][dd]     = a0;
    *(uint4*)&t[s][dd + 8] = a1;
  }
  __syncthreads();
  {
    int d = tid >> 2, sp = (tid & 3) * 16;
    unsigned short buf[16];
#pragma unroll
    for (int e = 0; e < 16; e++) {
      bf16 v = t[sp + e][d];
      buf[e] = *(unsigned short*)&v;
    }
    bf16* dst = &Vt[((size_t)bh*DHq + d)*Sq + sc_*64 + sp];
    *(uint4*)dst       = *(uint4*)&buf[0];
    *(uint4*)(dst + 8) = *(uint4*)&buf[8];
  }
}

// ---------------- MFMA fused attention (dense / exact top-K sparse) ----------------
template<int SPARSE>
__global__ __launch_bounds__(256, 4)
void attn_kernel(const bf16* __restrict__ Q, const bf16* __restrict__ K,
                 const bf16* __restrict__ Vt, bf16* __restrict__ O)
{
  const int PAST = 1032;
  __shared__ bf16 pa[16*PAST];
  __shared__ float partA[64], partB[64];
  __shared__ int cntb[2][64];

  int blk = blockIdx.x;
  int rb = blk & 63;
  int h  = (blk >> 6) & 15;
  int b  = blk >> 10;
  int tid = threadIdx.x, lane = tid & 63, wave = tid >> 6;
  int m = lane & 15, q = lane >> 4;
  size_t base = ((size_t)b*Sq)*Dq + (size_t)h*DHq;
  int q0 = rb*16;

  const bf16* qrow = &Q[base + (size_t)(q0+m)*Dq + q*8];
  bf16x8 aq0 = *(const bf16x8*)qrow;
  bf16x8 aq1 = *(const bf16x8*)(qrow + 32);

  f32x4 cc[16];
#pragma unroll
  for (int t = 0; t < 16; t++) {
    int j0 = wave*256 + t*16;
    const bf16* kp = &K[base + (size_t)(j0+m)*Dq + q*8];
    bf16x8 b0 = *(const bf16x8*)kp;
    bf16x8 b1 = *(const bf16x8*)(kp + 32);
    f32x4 c = {0.f,0.f,0.f,0.f};
    c = __builtin_amdgcn_mfma_f32_16x16x32_bf16(aq0, b0, c, 0, 0, 0);
    c = __builtin_amdgcn_mfma_f32_16x16x32_bf16(aq1, b1, c, 0, 0, 0);
#pragma unroll
    for (int r=0;r<4;r++) c[r] *= SCALEF;
    cc[t] = c;
  }

  unsigned lo[4] = {0u,0u,0u,0u};
  if (SPARSE) {
    int cnt_cur[4] = {Sq, Sq, Sq, Sq};
    for (int bit = 31; bit >= 0; bit--) {
      int par = bit & 1;
      unsigned cand[4];
      float candf[4];
      int c4[4] = {0,0,0,0};
#pragma unroll
      for (int r=0;r<4;r++) {
        cand[r] = lo[r] | (1u << bit);
        candf[r] = thr_decode(cand[r]);
      }
#pragma unroll
      for (int t=0;t<16;t++)
#pragma unroll
        for (int r=0;r<4;r++) c4[r] += (cc[t][r] >= candf[r]) ? 1 : 0;
#pragma unroll
      for (int o=1;o<16;o<<=1)
#pragma unroll
        for (int r=0;r<4;r++) c4[r] += __shfl_xor(c4[r], o);
      if (m == 0) {
#pragma unroll
        for (int r=0;r<4;r++) cntb[par][wave*16 + q*4 + r] = c4[r];
      }
      __syncthreads();
      int done = 1;
#pragma unroll
      for (int r=0;r<4;r++) {
        int row = q*4 + r;
        int tot = cntb[par][row] + cntb[par][16+row] + cntb[par][32+row] + cntb[par][48+row];
        if (tot >= Kq) { lo[r] = cand[r]; cnt_cur[r] = tot; }
        done &= (cnt_cur[r] == Kq) ? 1 : 0;
      }
      done &= __shfl_xor(done, 16);
      done &= __shfl_xor(done, 32);
      if (done) break;
    }
  }

  float mrow[4];
#pragma unroll
  for (int r=0;r<4;r++) {
    float v = -1e30f;
#pragma unroll
    for (int t=0;t<16;t++) v = fmaxf(v, cc[t][r]);
#pragma unroll
    for (int o=1;o<16;o<<=1) v = fmaxf(v, __shfl_xor(v, o));
    mrow[r] = v;
  }
  if (m == 0) {
#pragma unroll
    for (int r=0;r<4;r++) partA[wave*16 + q*4 + r] = mrow[r];
  }
  __syncthreads();
#pragma unroll
  for (int r=0;r<4;r++) {
    int row = q*4 + r;
    mrow[r] = fmaxf(fmaxf(partA[row], partA[16+row]), fmaxf(partA[32+row], partA[48+row]));
  }

  float thrf[4];
  if (SPARSE) {
#pragma unroll
    for (int r=0;r<4;r++) {
      thrf[r] = (!(lo[r] & 0x80000000u) && lo[r] <= 0x007FFFFFu)
                    ? -INFINITY : thr_decode(lo[r]);
    }
  }
  float rsum[4] = {0.f,0.f,0.f,0.f};
#pragma unroll
  for (int t=0;t<16;t++) {
    int col = wave*256 + t*16 + m;
#pragma unroll
    for (int r=0;r<4;r++) {
      float p;
      if (SPARSE) p = (cc[t][r] >= thrf[r]) ? __expf(cc[t][r] - mrow[r]) : 0.f;
      else        p = __expf(cc[t][r] - mrow[r]);
      rsum[r] += p;
      pa[(q*4+r)*PAST + col] = __float2bfloat16(p);
    }
  }
#pragma unroll
  for (int r=0;r<4;r++)
#pragma unroll
    for (int o=1;o<16;o<<=1) rsum[r] += __shfl_xor(rsum[r], o);
  if (m == 0) {
#pragma unroll
    for (int r=0;r<4;r++) partB[wave*16 + q*4 + r] = rsum[r];
  }
  __syncthreads();
#pragma unroll
  for (int r=0;r<4;r++) {
    int row = q*4 + r;
    rsum[r] = partB[row] + partB[16+row] + partB[32+row] + partB[48+row];
    rsum[r] = fmaxf(rsum[r], 1e-30f);
  }

  const bf16* vtp = &Vt[((size_t)(b*Hq + h)*DHq + wave*16 + m)*Sq];
  f32x4 oc = {0.f,0.f,0.f,0.f};
#pragma unroll 8
  for (int ks = 0; ks < 32; ks++) {
    bf16x8 af = *(const bf16x8*)&pa[m*PAST + ks*32 + q*8];
    bf16x8 bv = *(const bf16x8*)&vtp[ks*32 + q*8];
    oc = __builtin_amdgcn_mfma_f32_16x16x32_bf16(af, bv, oc, 0, 0, 0);
  }
#pragma unroll
  for (int r=0;r<4;r++) {
    O[base + (size_t)(q0 + q*4 + r)*Dq + wave*16 + m] = __float2bfloat16(oc[r] / rsum[r]);
  }
}

// ---------------- performer pass 1 (MFMA) ----------------
__global__ __launch_bounds__(256)
void perf_kv_mfma(const bf16* __restrict__ Kb, const bf16* __restrict__ Vt,
                  const bf16* __restrict__ wft, bf16* __restrict__ kvb,
                  float* __restrict__ zg)
{
  __shared__ bf16 pbuf[4][32*40];
  __shared__ float kvred[4][64*32];
  __shared__ float zred[4][32];

  int bh = blockIdx.x;
  int mg = blockIdx.y;
  int b = bh >> 4, h = bh & 15;
  int tid = threadIdx.x, lane = tid & 63, wave = tid >> 6;
  int ml = lane & 15, q = lane >> 4;
  size_t kbase = ((size_t)b*Sq)*Dq + (size_t)h*DHq;
  const bf16* vtb = Vt + (size_t)bh*DHq*Sq;
  int sw0 = wave*256;
  bf16* pw = pbuf[wave];

  bf16x8 awf[2][2];
#pragma unroll
  for (int t=0;t<2;t++) {
    const bf16* p = &wft[(size_t)(mg*32 + t*16 + ml)*DHq + q*8];
    awf[t][0] = *(const bf16x8*)p;
    awf[t][1] = *(const bf16x8*)(p + 32);
  }

  f32x4 acc[4][2];
#pragma unroll
  for (int dt=0;dt<4;dt++)
#pragma unroll
    for (int t=0;t<2;t++) acc[dt][t] = (f32x4){0.f,0.f,0.f,0.f};
  float zacc[2][4] = {{0.f,0.f,0.f,0.f},{0.f,0.f,0.f,0.f}};

  for (int st = 0; st < 8; st++) {
    int s0 = sw0 + st*32;
    f32x4 pk[2][2];
#pragma unroll
    for (int sc=0;sc<2;sc++) {
      const bf16* kp = &Kb[kbase + (size_t)(s0 + sc*16 + ml)*Dq + q*8];
      bf16x8 b0 = *(const bf16x8*)kp;
      bf16x8 b1 = *(const bf16x8*)(kp + 32);
#pragma unroll
      for (int t=0;t<2;t++) {
        f32x4 c = (f32x4){0.f,0.f,0.f,0.f};
        c = __builtin_amdgcn_mfma_f32_16x16x32_bf16(awf[t][0], b0, c, 0, 0, 0);
        c = __builtin_amdgcn_mfma_f32_16x16x32_bf16(awf[t][1], b1, c, 0, 0, 0);
        pk[t][sc] = c;
      }
    }
#pragma unroll
    for (int t=0;t<2;t++)
#pragma unroll
      for (int sc=0;sc<2;sc++)
#pragma unroll
        for (int r=0;r<4;r++) {
          float v = fmaxf(pk[t][sc][r], 0.f);
          zacc[t][r] += v;
          pw[(t*16 + q*4 + r)*40 + sc*16 + ml] = __float2bfloat16(v);
        }
#pragma unroll
    for (int dt=0;dt<4;dt++) {
      bf16x8 av = *(const bf16x8*)&vtb[(size_t)(dt*16 + ml)*Sq + s0 + q*8];
#pragma unroll
      for (int t=0;t<2;t++) {
        bf16x8 bp = *(const bf16x8*)&pw[(t*16 + ml)*40 + q*8];
        acc[dt][t] = __builtin_amdgcn_mfma_f32_16x16x32_bf16(av, bp, acc[dt][t], 0, 0, 0);
      }
    }
  }

#pragma unroll
  for (int dt=0;dt<4;dt++)
#pragma unroll
    for (int t=0;t<2;t++)
#pragma unroll
      for (int r=0;r<4;r++)
        kvred[wave][(dt*16 + q*4 + r)*32 + t*16 + ml] = acc[dt][t][r];
#pragma unroll
  for (int t=0;t<2;t++)
#pragma unroll
    for (int r=0;r<4;r++) {
      float v = zacc[t][r];
#pragma unroll
      for (int o=1;o<16;o<<=1) v += __shfl_xor(v, o);
      if (ml == 0) zred[wave][t*16 + q*4 + r] = v;
    }
  __syncthreads();
  for (int p = tid; p < 2048; p += 256) {
    float s = kvred[0][p] + kvred[1][p] + kvred[2][p] + kvred[3][p];
    int d = p >> 5, mloc = p & 31;
    kvb[(size_t)bh*(DHq*Mq) + d*Mq + mg*32 + mloc] = __float2bfloat16(s);
  }
  if (tid < 32) {
    float s = zred[0][tid] + zred[1][tid] + zred[2][tid] + zred[3][tid];
    zg[bh*Mq + mg*32 + tid] = s;
  }
}

// ---------------- performer pass 2 (MFMA) ----------------
__global__ __launch_bounds__(256)
void perf_out_mfma(const bf16* __restrict__ Q, const bf16* __restrict__ wft,
                   const bf16* __restrict__ kvb, const float* __restrict__ zg,
                   bf16* __restrict__ O)
{
  const int PQST = 264;
  __shared__ bf16 pa2[64*PQST];
  __shared__ float zs[Mq];

  int blk = blockIdx.x;
  int sc_ = blk & 15;
  int bh  = blk >> 4;
  int b = bh >> 4, h = bh & 15;
  int tid = threadIdx.x, lane = tid & 63, wave = tid >> 6;
  int ml = lane & 15, q = lane >> 4;
  size_t base = ((size_t)b*Sq)*Dq + (size_t)h*DHq;
  int s0 = sc_*64;

  zs[tid] = zg[bh*Mq + tid];

  const bf16* qp = &Q[base + (size_t)(s0 + wave*16 + ml)*Dq + q*8];
  bf16x8 aq0 = *(const bf16x8*)qp;
  bf16x8 aq1 = *(const bf16x8*)(qp + 32);
  __syncthreads();

  f32x4 pq[16];
#pragma unroll
  for (int mt=0;mt<16;mt++) {
    const bf16* wp = &wft[(size_t)(mt*16 + ml)*DHq + q*8];
    bf16x8 b0 = *(const bf16x8*)wp;
    bf16x8 b1 = *(const bf16x8*)(wp + 32);
    f32x4 c = (f32x4){0.f,0.f,0.f,0.f};
    c = __builtin_amdgcn_mfma_f32_16x16x32_bf16(aq0, b0, c, 0, 0, 0);
    c = __builtin_amdgcn_mfma_f32_16x16x32_bf16(aq1, b1, c, 0, 0, 0);
    pq[mt] = c;
  }

  float den[4] = {1e-6f, 1e-6f, 1e-6f, 1e-6f};
#pragma unroll
  for (int mt=0;mt<16;mt++)
#pragma unroll
    for (int r=0;r<4;r++) {
      float v = fmaxf(pq[mt][r], 0.f);
      den[r] += v * zs[mt*16 + ml];
      pa2[(wave*16 + q*4 + r)*PQST + mt*16 + ml] = __float2bfloat16(v);
    }
#pragma unroll
  for (int r=0;r<4;r++)
#pragma unroll
    for (int o=1;o<16;o<<=1) den[r] += __shfl_xor(den[r], o);
  __syncthreads();

  const bf16* kvp = kvb + (size_t)bh*(DHq*Mq);
  f32x4 oc[4];
#pragma unroll
  for (int dt=0;dt<4;dt++) oc[dt] = (f32x4){0.f,0.f,0.f,0.f};
#pragma unroll
  for (int ks=0; ks<8; ks++) {
    bf16x8 ap = *(const bf16x8*)&pa2[(wave*16 + ml)*PQST + ks*32 + q*8];
#pragma unroll
    for (int dt=0;dt<4;dt++) {
      bf16x8 bk = *(const bf16x8*)&kvp[(size_t)(dt*16 + ml)*Mq + ks*32 + q*8];
      oc[dt] = __builtin_amdgcn_mfma_f32_16x16x32_bf16(ap, bk, oc[dt], 0, 0, 0);
    }
  }
#pragma unroll
  for (int dt=0;dt<4;dt++)
#pragma unroll
    for (int r=0;r<4;r++)
      O[base + (size_t)(s0 + wave*16 + q*4 + r)*Dq + dt*16 + ml] =
          __float2bfloat16(oc[dt][r] / den[r]);
}

// ---------------- LayerNorm ----------------
template<typename IT>
__device__ void ln_body(float* buf, float* red, const IT* __restrict__ xb,
                        const void* Ap, const void* Bp,
                        const IT* __restrict__ g, const IT* __restrict__ be,
                        void* out, int mode)
{
  int row = blockIdx.x;
  int tid = threadIdx.x;
  size_t off = (size_t)row*Dq;
  for (int dd = tid; dd < Dq; dd += 256) {
    float v;
    if (mode == 0)      v = toF(xb[off+dd]) + toF(((const bf16*)Ap)[off+dd]);
    else if (mode == 1) v = toF(((const bf16*)Ap)[off+dd]) + toF(((const bf16*)Bp)[off+dd]);
    else if (mode == 3) {
      const bf16* P = (const bf16*)Ap;
      v = toF(xb[off+dd]);
#pragma unroll
      for (int p=0;p<6;p++) v += toF(P[(size_t)p*PLANE + off + dd]);
    }
    else                v = toF(((const bf16*)Ap)[off+dd]);
    buf[dd] = v;
  }
  __syncthreads();
  float s = 0.f, q = 0.f;
  for (int dd = tid; dd < Dq; dd += 256) { float v = buf[dd]; s += v; q += v*v; }
#pragma unroll
  for (int o=32;o>=1;o>>=1) { s += __shfl_xor(s,o); q += __shfl_xor(q,o); }
  int w = tid >> 6;
  if ((tid & 63) == 0) { red[w] = s; red[4+w] = q; }
  __syncthreads();
  if (tid == 0) {
    float S1 = red[0]+red[1]+red[2]+red[3];
    float Q1 = red[4]+red[5]+red[6]+red[7];
    float mu = S1 / (float)Dq;
    float var = Q1 / (float)Dq - mu*mu;
    red[8] = mu; red[9] = rsqrtf(fmaxf(var, 0.f) + 1e-5f);
  }
  __syncthreads();
  float mu = red[8], inv = red[9];
  for (int dd = tid; dd < Dq; dd += 256) {
    float v = (buf[dd]-mu)*inv*toF(g[dd]) + toF(be[dd]);
    if (mode == 2) stF((IT*)out, off+dd, v);
    else           stF((bf16*)out, off+dd, v);
  }
}

__global__ __launch_bounds__(256)
void ln_kernel(const int* __restrict__ flag, const void* xb, const void* A, const void* Bv,
               const void* g, const void* be, void* out, int mode)
{
  __shared__ float buf[Dq];
  __shared__ float red[10];
  if (*flag) ln_body<bf16>(buf, red, (const bf16*)xb, A, Bv, (const bf16*)g, (const bf16*)be, out, mode);
  else       ln_body<float>(buf, red, (const float*)xb, A, Bv, (const float*)g, (const float*)be, out, mode);
}

// ---------------- avg over S (v2: coalesced rows, atomic column partials; writes RAW SUMS) ----------------
__global__ __launch_bounds__(256)
void avg2_kernel(const int* __restrict__ flag, const void* __restrict__ x, float* __restrict__ avgsum)
{
  int b  = blockIdx.x >> 4;          // 2 batches x 16 s-chunks of 64 rows
  int sc = blockIdx.x & 15;
  int t = threadIdx.x;
  int c0 = t*4;
  float a0=0.f,a1=0.f,a2=0.f,a3=0.f;
  if (*flag) {
    const unsigned* X = (const unsigned*)x;      // bf16 pairs
    for (int s = sc*64; s < sc*64+64; s++) {
      size_t bi = (((size_t)(b*Sq + s))*Dq + c0) >> 1;
      unsigned u0 = X[bi], u1 = X[bi+1];
      a0 += __uint_as_float(u0 << 16);
      a1 += __uint_as_float(u0 & 0xFFFF0000u);
      a2 += __uint_as_float(u1 << 16);
      a3 += __uint_as_float(u1 & 0xFFFF0000u);
    }
  } else {
    const float* X = (const float*)x;
    for (int s = sc*64; s < sc*64+64; s++) {
      float4 v = *(const float4*)&X[((size_t)(b*Sq + s))*Dq + c0];
      a0 += v.x; a1 += v.y; a2 += v.z; a3 += v.w;
    }
  }
  atomicAdd(&avgsum[b*Dq + c0 + 0], a0);
  atomicAdd(&avgsum[b*Dq + c0 + 1], a1);
  atomicAdd(&avgsum[b*Dq + c0 + 2], a2);
  atomicAdd(&avgsum[b*Dq + c0 + 3], a3);
}

// ---------------- gate dots (one wave per 1024-length dot) ----------------
// blocks 0..63: g1 (256 outputs, 4/block). block 64: taa logits. block 65: ag logits.
// avgs holds RAW sums over S; divide by S inside.
template<typename IT>
__device__ void gdots_body(const float* __restrict__ avgs,
    const IT* __restrict__ w1, const IT* __restrict__ b1,
    const IT* __restrict__ taw, const IT* __restrict__ tab,
    const IT* __restrict__ agw, const IT* __restrict__ agb,
    float* __restrict__ g1b, float* __restrict__ lgb)
{
  int blk = blockIdx.x;
  int tid = threadIdx.x, lane = tid & 63, wave = tid >> 6;
  if (blk < 64) {
    int o = blk*4 + wave;
    int bb = o >> 7, j = o & 127;
    const float* av = avgs + bb*Dq;
    float a = 0.f;
#pragma unroll
    for (int k = 0; k < 16; k++) {
      int dd = k*64 + lane;
      a += av[dd] * toF(w1[dd*GATEq + j]);
    }
#pragma unroll
    for (int off=32; off>=1; off>>=1) a += __shfl_xor(a, off);
    if (lane == 0) g1b[o] = gelu_f(a*(1.f/(float)Sq) + toF(b1[j]));
  } else {
    int bb = wave >> 1, c = wave & 1;
    const float* av = avgs + bb*Dq;
    const IT* wm = (blk == 64) ? taw : agw;
    const IT* bm = (blk == 64) ? tab : agb;
    float a = 0.f;
#pragma unroll
    for (int k = 0; k < 16; k++) {
      int dd = k*64 + lane;
      a += av[dd] * toF(wm[dd*2 + c]);
    }
#pragma unroll
    for (int off=32; off>=1; off>>=1) a += __shfl_xor(a, off);
    if (lane == 0) lgb[(blk-64)*4 + wave] = a*(1.f/(float)Sq) + toF(bm[c]);
  }
}
__global__ __launch_bounds__(256)
void gate_dots_kernel(const int* __restrict__ flag, const float* avgs,
    const void* w1, const void* b1, const void* taw, const void* tab,
    const void* agw, const void* agb, float* g1b, float* lgb)
{
  if (*flag) gdots_body<bf16>(avgs, (const bf16*)w1,(const bf16*)b1,(const bf16*)taw,
      (const bf16*)tab,(const bf16*)agw,(const bf16*)agb, g1b, lgb);
  else gdots_body<float>(avgs, (const float*)w1,(const float*)b1,(const float*)taw,
      (const float*)tab,(const float*)agw,(const float*)agb, g1b, lgb);
}

// ---------------- gate finalize ----------------
template<typename IT>
__device__ void gfin_body(float* sh, const float* __restrict__ g1b, const float* __restrict__ lgb,
    const IT* __restrict__ w2, const IT* __restrict__ b2,
    float* __restrict__ cmb0, float* __restrict__ rs_tg0,
    float* __restrict__ rs_tg1, float* __restrict__ rs_ffn)
{
  int tid = threadIdx.x, lane = tid & 63, wave = tid >> 6;
  if (wave < 2) {
    float a = g1b[wave*128 + lane] * toF(w2[lane*2 + 1])
            + g1b[wave*128 + 64 + lane] * toF(w2[(64+lane)*2 + 1]);
#pragma unroll
    for (int off=32; off>=1; off>>=1) a += __shfl_xor(a, off);
    if (lane == 0) sh[wave] = 1.f/(1.f + __expf(-(a + toF(b2[1]))));
  }
  __syncthreads();
  if (tid < Bq) {
    int b = tid;
    float t0 = lgb[b*2], t1 = lgb[b*2+1];
    float m = fmaxf(t0,t1);
    float e0=__expf(t0-m), e1=__expf(t1-m), inv=1.f/(e0+e1);
    float tg0 = e0*inv, tg1 = e1*inv;
    float a0 = lgb[4+b*2], a1l = lgb[4+b*2+1];
    m = fmaxf(a0,a1l);
    float f0=__expf(a0-m), f1=__expf(a1l-m); inv = 1.f/(f0+f1);
    float ag0 = f0*inv, ag1 = f1*inv;
    cmb0[b] = ag0*DEPTHF;
    sh[2+b] = tg0*ag1*DEPTHF;
    sh[4+b] = tg1*ag1*DEPTHF;
    sh[6+b] = sh[b]*DEPTHF;
  }
  __syncthreads();
  for (int i = tid; i < BSq; i += 256) {
    int b = i >> 10;
    rs_tg0[i] = sh[2+b]; rs_tg1[i] = sh[4+b]; rs_ffn[i] = sh[6+b];
  }
}
__global__ __launch_bounds__(256)
void gate_fin_kernel(const int* __restrict__ flag, const float* g1b, const float* lgb,
    const void* w2, const void* b2, float* cmb0,
    float* rs_tg0, float* rs_tg1, float* rs_ffn)
{
  __shared__ float sh[8];
  if (*flag) gfin_body<bf16>(sh, g1b, lgb, (const bf16*)w2, (const bf16*)b2, cmb0, rs_tg0, rs_tg1, rs_ffn);
  else       gfin_body<float>(sh, g1b, lgb, (const float*)w2, (const float*)b2, cmb0, rs_tg0, rs_tg1, rs_ffn);
}

// ---------------- MoE router ----------------
template<typename IT>
__device__ void router_body(const IT* __restrict__ x, const IT* __restrict__ wr,
                            const IT* __restrict__ br, const float* __restrict__ cmb0,
                            float* __restrict__ gates_t)
{
  int row = blockIdx.x;
  int tid = threadIdx.x;
  size_t off = (size_t)row*Dq;
  float a0=0,a1=0,a2=0,a3=0;
  for (int dd = tid; dd < Dq; dd += 64) {
    float xv = toF(x[off+dd]);
    a0 += xv*toF(wr[dd*Eq+0]);
    a1 += xv*toF(wr[dd*Eq+1]);
    a2 += xv*toF(wr[dd*Eq+2]);
    a3 += xv*toF(wr[dd*Eq+3]);
  }
#pragma unroll
  for (int o=32;o>=1;o>>=1) {
    a0 += __shfl_xor(a0,o); a1 += __shfl_xor(a1,o);
    a2 += __shfl_xor(a2,o); a3 += __shfl_xor(a3,o);
  }
  if (tid == 0) {
    a0 += toF(br[0]); a1 += toF(br[1]); a2 += toF(br[2]); a3 += toF(br[3]);
    float m = fmaxf(fmaxf(a0,a1),fmaxf(a2,a3));
    float e0=__expf(a0-m), e1=__expf(a1-m), e2=__expf(a2-m), e3=__expf(a3-m);
    float inv = 1.f/(e0+e1+e2+e3);
    float sc = cmb0[row >> 10];
    gates_t[0*BSq+row]=e0*inv*sc; gates_t[1*BSq+row]=e1*inv*sc;
    gates_t[2*BSq+row]=e2*inv*sc; gates_t[3*BSq+row]=e3*inv*sc;
  }
}
__global__ __launch_bounds__(64)
void router_kernel(const int* __restrict__ flag, const void* x, const void* wr,
                   const void* br, const float* cmb0, float* gates_t)
{
  if (*flag) router_body<bf16>((const bf16*)x, (const bf16*)wr, (const bf16*)br, cmb0, gates_t);
  else       router_body<float>((const float*)x, (const float*)wr, (const float*)br, cmb0, gates_t);
}

extern "C" void kernel_launch(void* const* d_in, const int* in_sizes, int n_in,
                              void* d_out, int out_size, void* d_ws, size_t ws_size,
                              hipStream_t stream) {
  const void* x      = d_in[0];
  const void* arg_w1 = d_in[1];  const void* arg_b1 = d_in[2];
  const void* arg_w2 = d_in[3];  const void* arg_b2 = d_in[4];
  const void* moe_wr = d_in[5];  const void* moe_br = d_in[6];
  const void* moe_wq = d_in[7];  const void* moe_bq = d_in[8];
  const void* moe_wk = d_in[9];  const void* moe_bk = d_in[10];
  const void* moe_wv = d_in[11]; const void* moe_bv = d_in[12];
  const void* moe_wo = d_in[13]; const void* moe_bo = d_in[14];
  const void* sp_wq  = d_in[15]; const void* sp_bq  = d_in[16];
  const void* sp_wk  = d_in[17]; const void* sp_bk  = d_in[18];
  const void* sp_wv  = d_in[19]; const void* sp_bv  = d_in[20];
  const void* sp_wo  = d_in[21]; const void* sp_bo  = d_in[22];
  const void* pf_wq  = d_in[23]; const void* pf_bq  = d_in[24];
  const void* pf_wk  = d_in[25]; const void* pf_bk  = d_in[26];
  const void* pf_wv  = d_in[27]; const void* pf_bv  = d_in[28];
  const void* pf_wo  = d_in[29]; const void* pf_bo  = d_in[30];
  const void* pf_wf  = d_in[31];
  const void* taa_wg = d_in[32]; const void* taa_bg = d_in[33];
  const void* ag_w   = d_in[34]; const void* ag_b   = d_in[35];
  const void* ffn_w1 = d_in[36]; const void* ffn_b1 = d_in[37];
  const void* ffn_w2 = d_in[38]; const void* ffn_b2 = d_in[39];
  const void* n1_g   = d_in[40]; const void* n1_b   = d_in[41];
  const void* n2_g   = d_in[42]; const void* n2_b   = d_in[43];
  const void* n3_g   = d_in[44]; const void* n3_b   = d_in[45];

  char* w = (char*)d_ws;
  const size_t MB = 1024*1024;
  // phase 1 (attention):
  bf16* xb  = (bf16*)w;                 // [0,4)
  bf16* Qp  = (bf16*)(w + 4*MB);        // [4,28)  6 Q planes (attn out in place)
  bf16* KV  = (bf16*)(w + 28*MB);       // [28,44) K0,V0,K1,V1
  bf16* Vt  = (bf16*)(w + 44*MB);       // [44,52) Vt0,Vt1
  bf16* Pp  = (bf16*)(w + 28*MB);       // [28,52) 6 O-proj planes (over KV/Vt, dead)
  // phase 2 (FFN):
  bf16* x1    = (bf16*)(w + 4*MB);      // [4,8)
  bf16* ffn_h = (bf16*)(w + 8*MB);      // [8,24)
  float* partF= (float*)(w + 24*MB);    // [24,56) 4 f32 partial planes
  bf16* tmpb  = (bf16*)w;               // [0,4)  (xb dead)
  bf16* x2    = (bf16*)w;               // LN2 writes in place over tmpb (row-safe)
  // bookkeeping:
  char* book = w + 56*MB;
  float* rs_tg0 = (float*)book;
  float* rs_tg1 = rs_tg0 + BSq;
  float* rs_ffn = rs_tg1 + BSq;
  float* cmb0   = rs_ffn + BSq;
  float* avgp   = cmb0 + 16;
  float* gates_t= avgp + Bq*Dq;
  float* zb     = gates_t + Eq*BSq;
  float* g1b    = zb + Bq*Hq*Mq;
  float* lgb    = g1b + 256;
  int*   dflag  = (int*)(lgb + 8);
  bf16*  barena = (bf16*)(dflag + 16);
  bf16*  wft    = barena + 29696;
  bf16*  kvb    = (bf16*)(w + 57*MB);   // [57,58) performer kvT

  detect_kernel<<<1, 256, 0, stream>>>((const unsigned*)x, dflag);
  hipMemsetAsync(avgp, 0, (size_t)(Bq*Dq)*sizeof(float), stream);
  conv_x_kernel<<<BSq*Dq/1024, 256, 0, stream>>>(dflag, x, xb);
  pack_bias_kernel<<<1, 256, 0, stream>>>(dflag, barena,
      moe_bq, moe_bk, moe_bv, moe_bo, sp_bq, sp_bk, sp_bv, sp_bo,
      pf_bq, pf_bk, pf_bv, pf_bo, ffn_b1, ffn_b2);
  pack_wft_kernel<<<64, 256, 0, stream>>>(dflag, pf_wf, wft);
  avg2_kernel<<<Bq*16, 256, 0, stream>>>(dflag, x, avgp);
  gate_dots_kernel<<<66, 256, 0, stream>>>(dflag, avgp, arg_w1, arg_b1,
      taa_wg, taa_bg, ag_w, ag_b, g1b, lgb);
  gate_fin_kernel<<<1, 256, 0, stream>>>(dflag, g1b, lgb, arg_w2, arg_b2,
      cmb0, rs_tg0, rs_tg1, rs_ffn);
  router_kernel<<<BSq, 64, 0, stream>>>(dflag, x, moe_wr, moe_br, cmb0, gates_t);

  dim3 g6(16, 8, 6);
  dim3 gVT(Bq*Hq, Sq/64, 2);
  int nAttnBlk = Bq*Hq*(Sq/16);

  // ---- MoE expert attentions, paired ----
  for (int p = 0; p < 2; p++) {
    int e0 = 2*p, e1 = 2*p + 1;
    gemm6_k<<<g6, 256, 0, stream>>>(dflag, xb, 0L,
        moe_wq, moe_wk, moe_wv, moe_wq, moe_wk, moe_wv,
        (long)e0*DD, (long)e0*DD, (long)e0*DD, (long)e1*DD, (long)e1*DD, (long)e1*DD,
        e0*1024, e0*1024+4096, e0*1024+8192, e1*1024, e1*1024+4096, e1*1024+8192,
        nullptr, nullptr, nullptr, nullptr, nullptr, nullptr,
        Qp + (size_t)e0*PLANE, KV, KV + PLANE,
        Qp + (size_t)e1*PLANE, KV + 2*PLANE, KV + 3*PLANE,
        barena, Dq, Dq);
    vtrans_kernel<<<gVT, 256, 0, stream>>>(KV + PLANE, (long)(2*PLANE), Vt, (long)PLANE);
    attn_kernel<0><<<nAttnBlk, 256, 0, stream>>>(Qp + (size_t)e0*PLANE, KV, Vt, Qp + (size_t)e0*PLANE);
    attn_kernel<0><<<nAttnBlk, 256, 0, stream>>>(Qp + (size_t)e1*PLANE, KV + 2*PLANE, Vt + PLANE, Qp + (size_t)e1*PLANE);
  }

  // ---- sparse + performer QKV, paired ----
  gemm6_k<<<g6, 256, 0, stream>>>(dflag, xb, 0L,
      sp_wq, sp_wk, sp_wv, pf_wq, pf_wk, pf_wv,
      0L, 0L, 0L, 0L, 0L, 0L,
      16384, 17408, 18432, 20480, 21504, 22528,
      nullptr, nullptr, nullptr, nullptr, nullptr, nullptr,
      Qp + 4*PLANE, KV, KV + PLANE,
      Qp + 5*PLANE, KV + 2*PLANE, KV + 3*PLANE,
      barena, Dq, Dq);
  vtrans_kernel<<<gVT, 256, 0, stream>>>(KV + PLANE, (long)(2*PLANE), Vt, (long)PLANE);
  attn_kernel<1><<<nAttnBlk, 256, 0, stream>>>(Qp + 4*PLANE, KV, Vt, Qp + 4*PLANE);
  {
    dim3 gKV1(Bq*Hq, 8);
    perf_kv_mfma<<<gKV1, 256, 0, stream>>>(KV + 2*PLANE, Vt + PLANE, wft, kvb, zb);
  }
  perf_out_mfma<<<Bq*Hq*16, 256, 0, stream>>>(Qp + 5*PLANE, wft, kvb, zb, Qp + 5*PLANE);

  // ---- all six O-projections in one launch, each to its own plane ----
  gemm6_k<<<g6, 256, 0, stream>>>(dflag, Qp, (long)PLANE,
      moe_wo, moe_wo, moe_wo, moe_wo, sp_wo, pf_wo,
      0L, (long)DD, (long)2*DD, (long)3*DD, 0L, 0L,
      12288, 13312, 14336, 15360, 19456, 23552,
      gates_t, gates_t + BSq, gates_t + 2*BSq, gates_t + 3*BSq, rs_tg0, rs_tg1,
      Pp, Pp + PLANE, Pp + 2*PLANE, Pp + 3*PLANE, Pp + 4*PLANE, Pp + 5*PLANE,
      barena, Dq, Dq);

  // ---- LN1: x + sum of 6 planes -> x1 ----
  ln_kernel<<<BSq, 256, 0, stream>>>(dflag, x, Pp, nullptr, n1_g, n1_b, x1, 3);

  // ---- FFN ----
  gemm1_k<<<dim3(16, 32, 1), 256, 0, stream>>>(dflag, x1, Dq, ffn_w1,
      barena, 24576, nullptr, ffn_h, nullptr, 0L, FFq, Dq, 1, 0);
  gemm1_k<<<dim3(16, 8, 4), 256, 0, stream>>>(dflag, ffn_h, FFq, ffn_w2,
      nullptr, 0, nullptr, nullptr, partF, (long)PLANE, Dq, 1024, 0, 1024);
  combine_ffn2<<<BSq*Dq/1024, 256, 0, stream>>>(partF, barena, rs_ffn, tmpb);

  // ---- LN2, LN3 ----
  ln_kernel<<<BSq, 256, 0, stream>>>(dflag, nullptr, x1, tmpb, n2_g, n2_b, x2, 1);
  ln_kernel<<<BSq, 256, 0, stream>>>(dflag, nullptr, x2, nullptr, n3_g, n3_b, d_out, 2);
}